// Round 5
// baseline (619.638 us; speedup 1.0000x reference)
//
#include <hip/hip_runtime.h>
#include <math.h>

// Phasor attention via split-fp16 MFMA (fp16x2 error-free splitting, ~fp32 accuracy).
// B=2, T=1024, D=512, H=8.
// Round 5: 3-slot ring pipeline with counted vmcnt (T3+T4), fragment-order LDS
// staging (conflict-free canonical ds_read_b128), 512-thread blocks, setprio.

#define PI_F 3.14159274101257324f

typedef __attribute__((ext_vector_type(8))) _Float16 half8;
typedef __attribute__((ext_vector_type(4))) _Float16 half4;
typedef __attribute__((ext_vector_type(2))) _Float16 half2v;
typedef __attribute__((ext_vector_type(16))) float f32x16;
typedef unsigned int u32;

#define MFMA32(a, b, c) __builtin_amdgcn_mfma_f32_32x32x16_f16((a), (b), (c), 0, 0, 0)
// C/D layout for 32x32: col = lane&31, row = (reg&3) + 8*(reg>>2) + 4*(lane>>5)
#define ROWOF(r, ln) (((r) & 3) + 8 * ((r) >> 2) + 4 * ((ln) >> 5))

__device__ __forceinline__ void gll16(const void* g, void* l) {
    __builtin_amdgcn_global_load_lds(
        (const __attribute__((address_space(1))) u32*)g,
        (__attribute__((address_space(3))) u32*)l, 16, 0, 0);
}

__device__ __forceinline__ void split2(float x, _Float16& h, _Float16& l) {
    _Float16 hh = (_Float16)x;
    h = hh;
    l = (_Float16)((x - (float)hh) * 4096.0f);
}

// bijective XCD swizzle (nwg divisible by 8)
__device__ __forceinline__ int xcdswz(int bid, int nwg) {
    const int cpx = nwg >> 3;
    return (bid & 7) * cpx + (bid >> 3);
}

// ---- ring pipeline helpers (all GEMM kernels share this skeleton) ----------
// slot = 48KB; 3 slots; 6 gll16 units/thread/step (one fragment each: 1KB/wave).
// Fragment f of a plane (R row-tile, ks k-half, hl hi/lo):
//   LDS off = plane_base + (R*4 + ks*2 + hl)*1024 + lane*16   (conflict-free)
//   global  = plane_hl + (row0 + R*32 + (ln&31))*stride + ks*16 + (ln>>5)*8
#define SLOT 49152

#define ISSUE6(slotoff, kk)                                                  \
    _Pragma("unroll") for (int u_ = 0; u_ < 6; ++u_)                         \
        gll16(sp[u_] + (kk), lds + (slotoff) + dp[u_]);

#define PIPE_WAIT(s, NS)                                                     \
    if ((s) + 3 <= (NS))      asm volatile("s_waitcnt vmcnt(12)" ::: "memory"); \
    else if ((s) + 2 == (NS)) asm volatile("s_waitcnt vmcnt(6)" ::: "memory");  \
    else                      asm volatile("s_waitcnt vmcnt(0)" ::: "memory");  \
    __builtin_amdgcn_s_barrier();                                            \
    __builtin_amdgcn_sched_barrier(0);

#define PIPE_MID(s, NS)                                                      \
    asm volatile("s_waitcnt lgkmcnt(0)" ::: "memory");                       \
    __builtin_amdgcn_sched_barrier(0);                                       \
    __builtin_amdgcn_s_barrier();                                            \
    __builtin_amdgcn_sched_barrier(0);                                       \
    if ((s) + 3 < (NS)) { ISSUE6(off, ((s) + 3) * 64); }

// ---------------------------------------------------------------------------
// encode: x [2048*512] f32 -> phasor planes cos/sin hi/lo [2048][512] fp16.
// ---------------------------------------------------------------------------
__global__ __launch_bounds__(256) void encode_phasor(
    const float* __restrict__ x,
    _Float16* __restrict__ ch, _Float16* __restrict__ cl,
    _Float16* __restrict__ sh, _Float16* __restrict__ sl)
{
    const int idx = blockIdx.x * 256 + threadIdx.x;
    float4 v = ((const float4*)x)[idx];
    float cc[4], ss[4];
    sincosf(PI_F * v.x, &ss[0], &cc[0]);
    sincosf(PI_F * v.y, &ss[1], &cc[1]);
    sincosf(PI_F * v.z, &ss[2], &cc[2]);
    sincosf(PI_F * v.w, &ss[3], &cc[3]);
    half4 chv, clv, shv, slv;
#pragma unroll
    for (int q = 0; q < 4; ++q) {
        _Float16 a, b;
        split2(cc[q], a, b); chv[q] = a; clv[q] = b;
        split2(ss[q], a, b); shv[q] = a; slv[q] = b;
    }
    ((half4*)ch)[idx] = chv;
    ((half4*)cl)[idx] = clv;
    ((half4*)sh)[idx] = shv;
    ((half4*)sl)[idx] = slv;
}

// ---------------------------------------------------------------------------
// tsplit64: w [h][K][N] f32 -> transposed split planes th/tl [h][N][K] fp16.
// ---------------------------------------------------------------------------
__global__ __launch_bounds__(256) void tsplit64(
    const float* __restrict__ w, _Float16* __restrict__ th, _Float16* __restrict__ tl,
    int K, int N)
{
    const int kt = blockIdx.x, ntile = blockIdx.y, h = blockIdx.z;
    const int k0 = kt * 64, n0 = ntile * 64;
    __shared__ float T[64][65];
    const int tid = threadIdx.x;
    const float* wb = w + (size_t)h * K * N;
    {
        const int r = tid >> 4, c4 = (tid & 15) * 4;
#pragma unroll
        for (int rr = 0; rr < 64; rr += 16) {
            float4 v = *(const float4*)&wb[(size_t)(k0 + rr + r) * N + n0 + c4];
            T[rr + r][c4 + 0] = v.x; T[rr + r][c4 + 1] = v.y;
            T[rr + r][c4 + 2] = v.z; T[rr + r][c4 + 3] = v.w;
        }
    }
    __syncthreads();
    {
        const int n = tid >> 2, kq = (tid & 3) * 16;
        half8 hv[2], lv[2];
#pragma unroll
        for (int q = 0; q < 16; ++q) {
            float f = T[kq + q][n];
            _Float16 hh, ll; split2(f, hh, ll);
            hv[q >> 3][q & 7] = hh; lv[q >> 3][q & 7] = ll;
        }
        _Float16* oh = th + ((size_t)h * N + n0 + n) * K + k0 + kq;
        _Float16* ol = tl + ((size_t)h * N + n0 + n) * K + k0 + kq;
        *(half8*)oh = hv[0]; *(half8*)(oh + 8) = hv[1];
        *(half8*)ol = lv[0]; *(half8*)(ol + 8) = lv[1];
    }
}

// ---------------------------------------------------------------------------
// proj_qk: y = phasor(x) @ w + bias -> normalize -> fp16 split phasors (c,s
// interleaved). Block 64(m) x 256(n), 8 waves (2x4), wave-tile 32x64, BK=32.
// LDS slot: [Xc 8K][Xs 8K][W 32K]. blockIdx.z: 0=query, 1=key.
// ---------------------------------------------------------------------------
__global__ __launch_bounds__(512, 2) void proj_qk(
    const _Float16* __restrict__ qch, const _Float16* __restrict__ qcl,
    const _Float16* __restrict__ qsh, const _Float16* __restrict__ qsl,
    const _Float16* __restrict__ kch, const _Float16* __restrict__ kcl,
    const _Float16* __restrict__ ksh, const _Float16* __restrict__ ksl,
    const _Float16* __restrict__ wqh, const _Float16* __restrict__ wql,
    const _Float16* __restrict__ wkh, const _Float16* __restrict__ wkl,
    const float* __restrict__ bq, const float* __restrict__ bk,
    _Float16* __restrict__ qzh, _Float16* __restrict__ qzl,
    _Float16* __restrict__ kzh, _Float16* __restrict__ kzl,
    int h0, int hcnt)
{
    const int inp = blockIdx.z;
    const _Float16* xch = inp ? kch : qch;
    const _Float16* xcl = inp ? kcl : qcl;
    const _Float16* xsh = inp ? ksh : qsh;
    const _Float16* xsl = inp ? ksl : qsl;
    const _Float16* wth = inp ? wkh : wqh;
    const _Float16* wtl = inp ? wkl : wql;
    const float* bias = inp ? bk : bq;
    _Float16* ozh = inp ? kzh : qzh;
    _Float16* ozl = inp ? kzl : qzl;

    const int m0 = blockIdx.x * 64;
    const int hc = blockIdx.y >> 1;
    const int n0h = (blockIdx.y & 1) * 256;
    __shared__ char lds[147456];
    const int tid = threadIdx.x, wv = tid >> 6, ln = tid & 63;
    const int wr = wv >> 2, wc = wv & 3, lm32 = ln & 31;

    // staging setup: units 0: Xc(8 frags) 1: Xs 2-5: W(32 frags)
    const char* sp[6]; int dp[6];
#pragma unroll
    for (int u = 0; u < 6; ++u) {
        const int g = u * 8 + wv;
        const _Float16 *ph, *pl; int row0, stride; int f;
        if (g < 8)       { f = g;      ph = xch; pl = xcl; row0 = m0; stride = 512; }
        else if (g < 16) { f = g - 8;  ph = xsh; pl = xsl; row0 = m0; stride = 512; }
        else             { f = g - 16;
                           ph = wth + (size_t)hc * 262144;
                           pl = wtl + (size_t)hc * 262144;
                           row0 = n0h; stride = 512; }
        const int R = f >> 2, ks = (f >> 1) & 1, hl = f & 1;
        sp[u] = (const char*)((hl ? pl : ph)
                + (size_t)(row0 + R * 32 + (ln & 31)) * stride
                + ks * 16 + (ln >> 5) * 8);
        dp[u] = u * 8192 + tid * 16;
    }

    f32x16 ach[2] = {}, acl[2] = {}, ash[2] = {}, asl[2] = {};

    ISSUE6(0, 0); ISSUE6(SLOT, 64); ISSUE6(2 * SLOT, 128);
    int off = 0;
    const int NS = 16;
    for (int s = 0; s < NS; ++s) {
        PIPE_WAIT(s, NS);
        half8 xc[2][2], xs[2][2], w[2][2][2];
#pragma unroll
        for (int ks = 0; ks < 2; ++ks)
#pragma unroll
            for (int hl = 0; hl < 2; ++hl) {
                xc[ks][hl] = *(const half8*)(lds + off + (wr * 4 + ks * 2 + hl) * 1024 + ln * 16);
                xs[ks][hl] = *(const half8*)(lds + off + 8192 + (wr * 4 + ks * 2 + hl) * 1024 + ln * 16);
#pragma unroll
                for (int j = 0; j < 2; ++j)
                    w[ks][j][hl] = *(const half8*)(lds + off + 16384
                        + ((wc * 2 + j) * 4 + ks * 2 + hl) * 1024 + ln * 16);
            }
        PIPE_MID(s, NS);
        __builtin_amdgcn_s_setprio(1);
#pragma unroll
        for (int ks = 0; ks < 2; ++ks)
#pragma unroll
            for (int j = 0; j < 2; ++j) {
                ach[j] = MFMA32(xc[ks][0], w[ks][j][0], ach[j]);
                acl[j] = MFMA32(xc[ks][0], w[ks][j][1], acl[j]);
                acl[j] = MFMA32(xc[ks][1], w[ks][j][0], acl[j]);
                ash[j] = MFMA32(xs[ks][0], w[ks][j][0], ash[j]);
                asl[j] = MFMA32(xs[ks][0], w[ks][j][1], asl[j]);
                asl[j] = MFMA32(xs[ks][1], w[ks][j][0], asl[j]);
            }
        __builtin_amdgcn_s_setprio(0);
        off = (off == 2 * SLOT) ? 0 : off + SLOT;
    }

    const float LS = 1.0f / 4096.0f;
    const int b = m0 >> 10, tbase = m0 & 1023;
    const size_t zz = (size_t)(b * hcnt + hc);
#pragma unroll
    for (int j = 0; j < 2; ++j) {
        const int nloc = wc * 64 + j * 32 + lm32;
        const float bval = bias[(size_t)(h0 + hc) * 512 + n0h + nloc];
#pragma unroll
        for (int r = 0; r < 16; ++r) {
            const int mloc = wr * 32 + ROWOF(r, ln);
            float yc = ach[j][r] + acl[j][r] * LS + bval;
            float ys = ash[j][r] + asl[j][r] * LS;
            float inv = 1.0f / sqrtf(fmaxf(yc * yc + ys * ys, 1e-36f));
            float c = yc * inv, sn = ys * inv;
            _Float16 chh, chl, shh, shl;
            split2(c, chh, chl); split2(sn, shh, shl);
            const size_t offo = (zz * 1024 + tbase + mloc) * 1024 + 2 * (n0h + nloc);
            half2v hv, lv;
            hv[0] = chh; hv[1] = shh; lv[0] = chl; lv[1] = shl;
            *(half2v*)(ozh + offo) = hv;
            *(half2v*)(ozl + offo) = lv;
        }
    }
}

// ---------------------------------------------------------------------------
// proj_v: same GEMM, epilogue writes transposed vT planes [Z][512 d][1024 t]
// via LDS transpose (144KB: 4 planes x [256 d][72 t]).
// ---------------------------------------------------------------------------
__global__ __launch_bounds__(512, 2) void proj_v(
    const _Float16* __restrict__ xch, const _Float16* __restrict__ xcl,
    const _Float16* __restrict__ xsh, const _Float16* __restrict__ xsl,
    const _Float16* __restrict__ wth, const _Float16* __restrict__ wtl,
    const float* __restrict__ bias,
    _Float16* __restrict__ vch, _Float16* __restrict__ vcl,
    _Float16* __restrict__ vsh, _Float16* __restrict__ vsl,
    int h0, int hcnt)
{
    const int m0 = blockIdx.x * 64;
    const int hc = blockIdx.y >> 1;
    const int n0h = (blockIdx.y & 1) * 256;
    __shared__ char lds[147456];
    const int tid = threadIdx.x, wv = tid >> 6, ln = tid & 63;
    const int wr = wv >> 2, wc = wv & 3, lm32 = ln & 31;

    const char* sp[6]; int dp[6];
#pragma unroll
    for (int u = 0; u < 6; ++u) {
        const int g = u * 8 + wv;
        const _Float16 *ph, *pl; int row0, stride; int f;
        if (g < 8)       { f = g;      ph = xch; pl = xcl; row0 = m0; stride = 512; }
        else if (g < 16) { f = g - 8;  ph = xsh; pl = xsl; row0 = m0; stride = 512; }
        else             { f = g - 16;
                           ph = wth + (size_t)hc * 262144;
                           pl = wtl + (size_t)hc * 262144;
                           row0 = n0h; stride = 512; }
        const int R = f >> 2, ks = (f >> 1) & 1, hl = f & 1;
        sp[u] = (const char*)((hl ? pl : ph)
                + (size_t)(row0 + R * 32 + (ln & 31)) * stride
                + ks * 16 + (ln >> 5) * 8);
        dp[u] = u * 8192 + tid * 16;
    }

    f32x16 ach[2] = {}, acl[2] = {}, ash[2] = {}, asl[2] = {};

    ISSUE6(0, 0); ISSUE6(SLOT, 64); ISSUE6(2 * SLOT, 128);
    int off = 0;
    const int NS = 16;
    for (int s = 0; s < NS; ++s) {
        PIPE_WAIT(s, NS);
        half8 xc[2][2], xs[2][2], w[2][2][2];
#pragma unroll
        for (int ks = 0; ks < 2; ++ks)
#pragma unroll
            for (int hl = 0; hl < 2; ++hl) {
                xc[ks][hl] = *(const half8*)(lds + off + (wr * 4 + ks * 2 + hl) * 1024 + ln * 16);
                xs[ks][hl] = *(const half8*)(lds + off + 8192 + (wr * 4 + ks * 2 + hl) * 1024 + ln * 16);
#pragma unroll
                for (int j = 0; j < 2; ++j)
                    w[ks][j][hl] = *(const half8*)(lds + off + 16384
                        + ((wc * 2 + j) * 4 + ks * 2 + hl) * 1024 + ln * 16);
            }
        PIPE_MID(s, NS);
        __builtin_amdgcn_s_setprio(1);
#pragma unroll
        for (int ks = 0; ks < 2; ++ks)
#pragma unroll
            for (int j = 0; j < 2; ++j) {
                ach[j] = MFMA32(xc[ks][0], w[ks][j][0], ach[j]);
                acl[j] = MFMA32(xc[ks][0], w[ks][j][1], acl[j]);
                acl[j] = MFMA32(xc[ks][1], w[ks][j][0], acl[j]);
                ash[j] = MFMA32(xs[ks][0], w[ks][j][0], ash[j]);
                asl[j] = MFMA32(xs[ks][0], w[ks][j][1], asl[j]);
                asl[j] = MFMA32(xs[ks][1], w[ks][j][0], asl[j]);
            }
        __builtin_amdgcn_s_setprio(0);
        off = (off == 2 * SLOT) ? 0 : off + SLOT;
    }

    const float LS = 1.0f / 4096.0f;
    const int b = m0 >> 10, tbase = m0 & 1023;
    const size_t zz = (size_t)(b * hcnt + hc);
    __syncthreads();
    // transpose: planes ch,cl,sh,sl each [256 d][72 t] fp16
#pragma unroll
    for (int j = 0; j < 2; ++j) {
        const int dloc = wc * 64 + j * 32 + lm32;
        const float bval = bias[(size_t)(h0 + hc) * 512 + n0h + dloc];
#pragma unroll
        for (int r = 0; r < 16; ++r) {
            const int tloc = wr * 32 + ROWOF(r, ln);
            float yc = ach[j][r] + acl[j][r] * LS + bval;
            float ys = ash[j][r] + asl[j][r] * LS;
            float inv = 1.0f / sqrtf(fmaxf(yc * yc + ys * ys, 1e-36f));
            float c = yc * inv, sn = ys * inv;
            _Float16 chh, chl, shh, shl;
            split2(c, chh, chl); split2(sn, shh, shl);
            ((_Float16*)(lds +      0))[dloc * 72 + tloc] = chh;
            ((_Float16*)(lds +  36864))[dloc * 72 + tloc] = chl;
            ((_Float16*)(lds +  73728))[dloc * 72 + tloc] = shh;
            ((_Float16*)(lds + 110592))[dloc * 72 + tloc] = shl;
        }
    }
    __syncthreads();
    {
        const int p = tid >> 7;
        _Float16* outp = (p == 0) ? vch : (p == 1) ? vcl : (p == 2) ? vsh : vsl;
        const int dl = (tid & 127) * 2;
#pragma unroll
        for (int dd = 0; dd < 2; ++dd) {
            const _Float16* srcT = (const _Float16*)(lds + p * 36864) + (dl + dd) * 72;
            _Float16* dst = outp + (zz * 512 + n0h + dl + dd) * 1024 + tbase;
#pragma unroll
            for (int q = 0; q < 8; ++q)
                *(half8*)(dst + q * 8) = *(const half8*)(srcT + q * 8);
        }
    }
}

// ---------------------------------------------------------------------------
// scores: S[z][t][T] = (qz . kz)/512, K=1024 (c,s interleaved).
// Block 128(q) x 256(k), 8 waves (2x4), wave-tile 64x64, BK=32.
// LDS slot: [A 16K][B 32K]. 1D grid XCD-swizzled.
// ---------------------------------------------------------------------------
__global__ __launch_bounds__(512, 2) void scores_mfma(
    const _Float16* __restrict__ qzh, const _Float16* __restrict__ qzl,
    const _Float16* __restrict__ kzh, const _Float16* __restrict__ kzl,
    float* __restrict__ S, int Z)
{
    const int wg = xcdswz(blockIdx.x, Z * 32);
    const int z = wg >> 5;
    const int rem = wg & 31;
    const int m0 = (rem & 7) << 7, n0 = (rem >> 3) << 8;
    __shared__ char lds[147456];
    const size_t zb = (size_t)z << 20;
    const int tid = threadIdx.x, wv = tid >> 6, ln = tid & 63;
    const int wr = wv >> 2, wc = wv & 3, lm32 = ln & 31;

    const char* sp[6]; int dp[6];
#pragma unroll
    for (int u = 0; u < 6; ++u) {
        const int g = u * 8 + wv;
        const _Float16 *ph, *pl; int row0; int f;
        if (g < 16) { f = g;      ph = qzh + zb; pl = qzl + zb; row0 = m0; }
        else        { f = g - 16; ph = kzh + zb; pl = kzl + zb; row0 = n0; }
        const int R = f >> 2, ks = (f >> 1) & 1, hl = f & 1;
        sp[u] = (const char*)((hl ? pl : ph)
                + (size_t)(row0 + R * 32 + (ln & 31)) * 1024
                + ks * 16 + (ln >> 5) * 8);
        dp[u] = u * 8192 + tid * 16;
    }

    f32x16 acch[2][2] = {}, accl[2][2] = {};

    ISSUE6(0, 0); ISSUE6(SLOT, 64); ISSUE6(2 * SLOT, 128);
    int off = 0;
    const int NS = 32;
    for (int s = 0; s < NS; ++s) {
        PIPE_WAIT(s, NS);
        half8 ah[2][2], al[2][2], bh[2][2], bl[2][2];
#pragma unroll
        for (int ks = 0; ks < 2; ++ks)
#pragma unroll
            for (int i = 0; i < 2; ++i) {
                const int Ra = (wr * 2 + i) * 4 + ks * 2;
                ah[ks][i] = *(const half8*)(lds + off + Ra * 1024 + ln * 16);
                al[ks][i] = *(const half8*)(lds + off + (Ra + 1) * 1024 + ln * 16);
                const int Rb = (wc * 2 + i) * 4 + ks * 2;
                bh[ks][i] = *(const half8*)(lds + off + 16384 + Rb * 1024 + ln * 16);
                bl[ks][i] = *(const half8*)(lds + off + 16384 + (Rb + 1) * 1024 + ln * 16);
            }
        PIPE_MID(s, NS);
        __builtin_amdgcn_s_setprio(1);
#pragma unroll
        for (int ks = 0; ks < 2; ++ks)
#pragma unroll
            for (int i = 0; i < 2; ++i)
#pragma unroll
                for (int j = 0; j < 2; ++j) {
                    acch[i][j] = MFMA32(ah[ks][i], bh[ks][j], acch[i][j]);
                    accl[i][j] = MFMA32(ah[ks][i], bl[ks][j], accl[i][j]);
                    accl[i][j] = MFMA32(al[ks][i], bh[ks][j], accl[i][j]);
                }
        __builtin_amdgcn_s_setprio(0);
        off = (off == 2 * SLOT) ? 0 : off + SLOT;
    }
    const float LS = 1.0f / 4096.0f, SC = 1.0f / 512.0f;
#pragma unroll
    for (int i = 0; i < 2; ++i)
#pragma unroll
        for (int j = 0; j < 2; ++j)
#pragma unroll
            for (int r = 0; r < 16; ++r) {
                const int row = m0 + wr * 64 + i * 32 + ROWOF(r, ln);
                const int col = n0 + wc * 64 + j * 32 + lm32;
                S[zb + (size_t)row * 1024 + col] =
                    (acch[i][j][r] + accl[i][j][r] * LS) * SC;
            }
}

// ---------------------------------------------------------------------------
// softmax rows of 1024 (max-subtracted); write P fp16 hi/lo split in place.
// ---------------------------------------------------------------------------
__global__ __launch_bounds__(256) void softmax_split(float* __restrict__ S)
{
    const size_t row = blockIdx.x;
    float* p = S + row * 1024;
    const int tid = threadIdx.x;
    float4 v = ((const float4*)p)[tid];
    float m = fmaxf(fmaxf(v.x, v.y), fmaxf(v.z, v.w));
#pragma unroll
    for (int off = 32; off >= 1; off >>= 1)
        m = fmaxf(m, __shfl_xor(m, off));
    __shared__ float redm[4], reds[4];
    const int wid = tid >> 6, lane = tid & 63;
    if (lane == 0) redm[wid] = m;
    __syncthreads();
    m = fmaxf(fmaxf(redm[0], redm[1]), fmaxf(redm[2], redm[3]));
    float4 e;
    e.x = expf(v.x - m); e.y = expf(v.y - m);
    e.z = expf(v.z - m); e.w = expf(v.w - m);
    float s = (e.x + e.y) + (e.z + e.w);
#pragma unroll
    for (int off = 32; off >= 1; off >>= 1)
        s += __shfl_xor(s, off);
    if (lane == 0) reds[wid] = s;
    __syncthreads();
    s = (reds[0] + reds[1]) + (reds[2] + reds[3]);
    e.x /= s; e.y /= s; e.z /= s; e.w /= s;
    __syncthreads();
    _Float16* ph = (_Float16*)p;
    half4 hv, lv;
    _Float16 a, b;
    split2(e.x, a, b); hv[0] = a; lv[0] = b;
    split2(e.y, a, b); hv[1] = a; lv[1] = b;
    split2(e.z, a, b); hv[2] = a; lv[2] = b;
    split2(e.w, a, b); hv[3] = a; lv[3] = b;
    *(half4*)(ph + tid * 4) = hv;
    *(half4*)(ph + 1024 + tid * 4) = lv;
}

// ---------------------------------------------------------------------------
// pv: out[z][t][d] = sum_T P[t][T]*vz[T][d], normalize, split, write rcs planes
// [2048][4096]. Block 128(t) x 128(d), 8 waves (2x4), wave-tile 64x32, BK=32.
// LDS slot: [P 16K][Vc 16K][Vs 16K].
// ---------------------------------------------------------------------------
__global__ __launch_bounds__(512, 2) void pv_mfma(
    const _Float16* __restrict__ P,
    const _Float16* __restrict__ vch, const _Float16* __restrict__ vcl,
    const _Float16* __restrict__ vsh, const _Float16* __restrict__ vsl,
    _Float16* __restrict__ rch, _Float16* __restrict__ rcl,
    _Float16* __restrict__ rsh, _Float16* __restrict__ rsl,
    int h0, int hcnt, int Z)
{
    const int wg = xcdswz(blockIdx.x, Z * 32);
    const int z = wg >> 5;
    const int rem = wg & 31;
    const int m0 = (rem & 7) << 7, n0 = (rem >> 3) << 7;
    __shared__ char lds[147456];
    const int tid = threadIdx.x, wv = tid >> 6, ln = tid & 63;
    const int wr = wv >> 2, wc = wv & 3, lm32 = ln & 31;

    const _Float16* Pb = P + (size_t)z * 1024 * 2048;
    const size_t vb = (size_t)z * 512 * 1024;
    const char* sp[6]; int dp[6];
#pragma unroll
    for (int u = 0; u < 6; ++u) {
        const int g = u * 8 + wv;
        const _Float16 *ph, *pl; int row0, stride; int f;
        if (g < 16)      { f = g;      ph = Pb; pl = Pb + 1024; row0 = m0; stride = 2048; }
        else if (g < 32) { f = g - 16; ph = vch + vb; pl = vcl + vb; row0 = n0; stride = 1024; }
        else             { f = g - 32; ph = vsh + vb; pl = vsl + vb; row0 = n0; stride = 1024; }
        const int R = f >> 2, ks = (f >> 1) & 1, hl = f & 1;
        sp[u] = (const char*)((hl ? pl : ph)
                + (size_t)(row0 + R * 32 + (ln & 31)) * stride
                + ks * 16 + (ln >> 5) * 8);
        dp[u] = u * 8192 + tid * 16;
    }

    f32x16 ac_h[2] = {}, ac_l[2] = {}, as_h[2] = {}, as_l[2] = {};

    ISSUE6(0, 0); ISSUE6(SLOT, 64); ISSUE6(2 * SLOT, 128);
    int off = 0;
    const int NS = 32;
    for (int s = 0; s < NS; ++s) {
        PIPE_WAIT(s, NS);
        half8 ph_[2][2], pl_[2][2], vc[2][2], vs[2][2];
#pragma unroll
        for (int ks = 0; ks < 2; ++ks) {
#pragma unroll
            for (int i = 0; i < 2; ++i) {
                const int Ra = (wr * 2 + i) * 4 + ks * 2;
                ph_[ks][i] = *(const half8*)(lds + off + Ra * 1024 + ln * 16);
                pl_[ks][i] = *(const half8*)(lds + off + (Ra + 1) * 1024 + ln * 16);
            }
            const int Rv = wc * 4 + ks * 2;
            vc[ks][0] = *(const half8*)(lds + off + 16384 + Rv * 1024 + ln * 16);
            vc[ks][1] = *(const half8*)(lds + off + 16384 + (Rv + 1) * 1024 + ln * 16);
            vs[ks][0] = *(const half8*)(lds + off + 32768 + Rv * 1024 + ln * 16);
            vs[ks][1] = *(const half8*)(lds + off + 32768 + (Rv + 1) * 1024 + ln * 16);
        }
        PIPE_MID(s, NS);
        __builtin_amdgcn_s_setprio(1);
#pragma unroll
        for (int ks = 0; ks < 2; ++ks)
#pragma unroll
            for (int i = 0; i < 2; ++i) {
                ac_h[i] = MFMA32(ph_[ks][i], vc[ks][0], ac_h[i]);
                ac_l[i] = MFMA32(ph_[ks][i], vc[ks][1], ac_l[i]);
                ac_l[i] = MFMA32(pl_[ks][i], vc[ks][0], ac_l[i]);
                as_h[i] = MFMA32(ph_[ks][i], vs[ks][0], as_h[i]);
                as_l[i] = MFMA32(ph_[ks][i], vs[ks][1], as_l[i]);
                as_l[i] = MFMA32(pl_[ks][i], vs[ks][0], as_l[i]);
            }
        __builtin_amdgcn_s_setprio(0);
        off = (off == 2 * SLOT) ? 0 : off + SLOT;
    }
    const float LS = 1.0f / 4096.0f;
    const int b = z / hcnt, hg = h0 + z % hcnt;
#pragma unroll
    for (int i = 0; i < 2; ++i)
#pragma unroll
        for (int r = 0; r < 16; ++r) {
            const int t = m0 + wr * 64 + i * 32 + ROWOF(r, ln);
            const int d = n0 + wc * 32 + lm32;
            float zc = ac_h[i][r] + ac_l[i][r] * LS;
            float zs = as_h[i][r] + as_l[i][r] * LS;
            float inv = 1.0f / sqrtf(fmaxf(zc * zc + zs * zs, 1e-36f));
            float c = zc * inv, sn = zs * inv;
            _Float16 chh, chl, shh, shl;
            split2(c, chh, chl); split2(sn, shh, shl);
            const size_t offo = ((size_t)(b * 1024 + t)) * 4096 + (size_t)hg * 512 + d;
            rch[offo] = chh; rcl[offo] = chl; rsh[offo] = shh; rsl[offo] = shl;
        }
}

// ---------------------------------------------------------------------------
// final (K-split): partial z = rz @ wo over K range [ks*1024, +1024).
// Block 64(m) x 256(n), 8 waves (2x4), wave-tile 32x64, BK=32.
// LDS slot: [Rc 8K][Rs 8K][Wo 32K]. Writes f32 (zr,zi) partials.
// ---------------------------------------------------------------------------
__global__ __launch_bounds__(512, 2) void final_mfma(
    const _Float16* __restrict__ rch, const _Float16* __restrict__ rcl,
    const _Float16* __restrict__ rsh, const _Float16* __restrict__ rsl,
    const _Float16* __restrict__ woh, const _Float16* __restrict__ wol,
    float* __restrict__ pbuf)
{
    const int m0 = blockIdx.x * 64, n0 = blockIdx.y * 256;
    const int kspl = blockIdx.z;
    const size_t kbase = (size_t)kspl * 1024;
    __shared__ char lds[147456];
    const int tid = threadIdx.x, wv = tid >> 6, ln = tid & 63;
    const int wr = wv >> 2, wc = wv & 3, lm32 = ln & 31;

    const char* sp[6]; int dp[6];
#pragma unroll
    for (int u = 0; u < 6; ++u) {
        const int g = u * 8 + wv;
        const _Float16 *ph, *pl; int row0; int f;
        if (g < 8)       { f = g;      ph = rch + kbase; pl = rcl + kbase; row0 = m0; }
        else if (g < 16) { f = g - 8;  ph = rsh + kbase; pl = rsl + kbase; row0 = m0; }
        else             { f = g - 16; ph = woh + kbase; pl = wol + kbase; row0 = n0; }
        const int R = f >> 2, ks = (f >> 1) & 1, hl = f & 1;
        sp[u] = (const char*)((hl ? pl : ph)
                + (size_t)(row0 + R * 32 + (ln & 31)) * 4096
                + ks * 16 + (ln >> 5) * 8);
        dp[u] = u * 8192 + tid * 16;
    }

    f32x16 rr_h[2] = {}, rr_l[2] = {}, ri_h[2] = {}, ri_l[2] = {};

    ISSUE6(0, 0); ISSUE6(SLOT, 64); ISSUE6(2 * SLOT, 128);
    int off = 0;
    const int NS = 32;
    for (int s = 0; s < NS; ++s) {
        PIPE_WAIT(s, NS);
        half8 rc[2][2], rs[2][2], w[2][2][2];
#pragma unroll
        for (int ks = 0; ks < 2; ++ks)
#pragma unroll
            for (int hl = 0; hl < 2; ++hl) {
                rc[ks][hl] = *(const half8*)(lds + off + (wr * 4 + ks * 2 + hl) * 1024 + ln * 16);
                rs[ks][hl] = *(const half8*)(lds + off + 8192 + (wr * 4 + ks * 2 + hl) * 1024 + ln * 16);
#pragma unroll
                for (int j = 0; j < 2; ++j)
                    w[ks][j][hl] = *(const half8*)(lds + off + 16384
                        + ((wc * 2 + j) * 4 + ks * 2 + hl) * 1024 + ln * 16);
            }
        PIPE_MID(s, NS);
        __builtin_amdgcn_s_setprio(1);
#pragma unroll
        for (int ks = 0; ks < 2; ++ks)
#pragma unroll
            for (int j = 0; j < 2; ++j) {
                rr_h[j] = MFMA32(rc[ks][0], w[ks][j][0], rr_h[j]);
                rr_l[j] = MFMA32(rc[ks][0], w[ks][j][1], rr_l[j]);
                rr_l[j] = MFMA32(rc[ks][1], w[ks][j][0], rr_l[j]);
                ri_h[j] = MFMA32(rs[ks][0], w[ks][j][0], ri_h[j]);
                ri_l[j] = MFMA32(rs[ks][0], w[ks][j][1], ri_l[j]);
                ri_l[j] = MFMA32(rs[ks][1], w[ks][j][0], ri_l[j]);
            }
        __builtin_amdgcn_s_setprio(0);
        off = (off == 2 * SLOT) ? 0 : off + SLOT;
    }
    const float LS = 1.0f / 4096.0f;
#pragma unroll
    for (int j = 0; j < 2; ++j) {
        const int ng = n0 + wc * 64 + j * 32 + lm32;
#pragma unroll
        for (int r = 0; r < 16; ++r) {
            const int mg = m0 + wr * 32 + ROWOF(r, ln);
            float zr = rr_h[j][r] + rr_l[j][r] * LS;
            float zi = ri_h[j][r] + ri_l[j][r] * LS;
            float2 v; v.x = zr; v.y = zi;
            *(float2*)&pbuf[((size_t)(kspl * 2048 + mg) * 512 + ng) * 2] = v;
        }
    }
}

// ---------------------------------------------------------------------------
// combine: out[m][n] = atan2(sum zi, sum zr + bo[n]) / pi
// ---------------------------------------------------------------------------
__global__ __launch_bounds__(256) void final_combine(
    const float* __restrict__ pbuf, const float* __restrict__ bo,
    float* __restrict__ out, int KS)
{
    const int m = blockIdx.x, t = threadIdx.x;
    float4 acc = {0.f, 0.f, 0.f, 0.f};
    for (int s = 0; s < KS; ++s) {
        float4 v = *(const float4*)&pbuf[(size_t)(s * 2048 + m) * 1024 + t * 4];
        acc.x += v.x; acc.y += v.y; acc.z += v.z; acc.w += v.w;
    }
    const int n0 = t * 2;
    out[(size_t)m * 512 + n0]     = atan2f(acc.y, acc.x + bo[n0]) / PI_F;
    out[(size_t)m * 512 + n0 + 1] = atan2f(acc.w, acc.z + bo[n0 + 1]) / PI_F;
}

// ---------------------------------------------------------------------------
extern "C" void kernel_launch(void* const* d_in, const int* in_sizes, int n_in,
                              void* d_out, int out_size, void* d_ws, size_t ws_size,
                              hipStream_t stream)
{
    (void)in_sizes; (void)n_in; (void)out_size;
    const float* query    = (const float*)d_in[0];
    const float* keyvalue = (const float*)d_in[1];
    const float* wq = (const float*)d_in[2];
    const float* bq = (const float*)d_in[3];
    const float* wk = (const float*)d_in[4];
    const float* bk = (const float*)d_in[5];
    const float* wv = (const float*)d_in[6];
    const float* bv = (const float*)d_in[7];
    const float* wo = (const float*)d_in[8];
    const float* bo = (const float*)d_in[9];
    float* out = (float*)d_out;

    // memory tiers: hcnt=8 ~304MB (rcs overlays qz); 4 ~228MB; 2 ~158MB.
    int hcnt;
    if (ws_size >= (size_t)320 * 1024 * 1024) hcnt = 8;
    else if (ws_size >= (size_t)240 * 1024 * 1024) hcnt = 4;
    else hcnt = 2;
    const int Z = 2 * hcnt;
    const int KS = (hcnt == 2) ? 2 : 4;

    char* p = (char*)d_ws;
    auto alloc = [&](size_t bytes) {
        char* r = p;
        p += (bytes + 255) & ~(size_t)255;
        return r;
    };
    const size_t PLX = (size_t)2048 * 512;
    _Float16* xq[4]; for (int i = 0; i < 4; ++i) xq[i] = (_Float16*)alloc(PLX * 2);
    _Float16* xk[4]; for (int i = 0; i < 4; ++i) xk[i] = (_Float16*)alloc(PLX * 2);
    _Float16* woT[2]; for (int i = 0; i < 2; ++i) woT[i] = (_Float16*)alloc((size_t)512 * 4096 * 2);
    const size_t WTE = (size_t)hcnt * 512 * 512;
    _Float16* wqT[2]; for (int i = 0; i < 2; ++i) wqT[i] = (_Float16*)alloc(WTE * 2);
    _Float16* wkT[2]; for (int i = 0; i < 2; ++i) wkT[i] = (_Float16*)alloc(WTE * 2);
    _Float16* wvT[2]; for (int i = 0; i < 2; ++i) wvT[i] = (_Float16*)alloc(WTE * 2);
    const size_t QZE = (size_t)Z * 1024 * 1024;
    _Float16* qz[2]; for (int i = 0; i < 2; ++i) qz[i] = (_Float16*)alloc(QZE * 2);
    _Float16* kz[2]; for (int i = 0; i < 2; ++i) kz[i] = (_Float16*)alloc(QZE * 2);
    float* S = (float*)alloc(QZE * 4);
    const size_t VTE = (size_t)Z * 512 * 1024;
    _Float16* vT[4]; for (int i = 0; i < 4; ++i) vT[i] = (_Float16*)alloc(VTE * 2);
    const size_t RCE = (size_t)2048 * 4096;
    _Float16* rcs[4];
    if (hcnt == 8) {
        for (int i = 0; i < 4; ++i) rcs[i] = (_Float16*)((char*)qz[0] + (size_t)i * RCE * 2);
    } else {
        for (int i = 0; i < 4; ++i) rcs[i] = (_Float16*)alloc(RCE * 2);
    }
    float* pbuf = (float*)kz[0];  // kz dead after scores of last chunk

    dim3 blk(256), blk5(512);

    encode_phasor<<<1024, blk, 0, stream>>>(query, xq[0], xq[1], xq[2], xq[3]);
    encode_phasor<<<1024, blk, 0, stream>>>(keyvalue, xk[0], xk[1], xk[2], xk[3]);
    tsplit64<<<dim3(64, 8, 1), blk, 0, stream>>>(wo, woT[0], woT[1], 4096, 512);

    for (int c = 0; c < 8 / hcnt; ++c) {
        const int h0 = c * hcnt;
        const float* wqc = wq + (size_t)h0 * 512 * 512;
        const float* wkc = wk + (size_t)h0 * 512 * 512;
        const float* wvc = wv + (size_t)h0 * 512 * 512;
        tsplit64<<<dim3(8, 8, hcnt), blk, 0, stream>>>(wqc, wqT[0], wqT[1], 512, 512);
        tsplit64<<<dim3(8, 8, hcnt), blk, 0, stream>>>(wkc, wkT[0], wkT[1], 512, 512);
        tsplit64<<<dim3(8, 8, hcnt), blk, 0, stream>>>(wvc, wvT[0], wvT[1], 512, 512);

        proj_qk<<<dim3(32, hcnt * 2, 2), blk5, 0, stream>>>(
            xq[0], xq[1], xq[2], xq[3], xk[0], xk[1], xk[2], xk[3],
            wqT[0], wqT[1], wkT[0], wkT[1], bq, bk,
            qz[0], qz[1], kz[0], kz[1], h0, hcnt);
        proj_v<<<dim3(32, hcnt * 2), blk5, 0, stream>>>(
            xk[0], xk[1], xk[2], xk[3], wvT[0], wvT[1], bv,
            vT[0], vT[1], vT[2], vT[3], h0, hcnt);

        scores_mfma<<<dim3(Z * 32), blk5, 0, stream>>>(qz[0], qz[1], kz[0], kz[1], S, Z);
        softmax_split<<<dim3(Z * 1024), blk, 0, stream>>>(S);
        pv_mfma<<<dim3(Z * 32), blk5, 0, stream>>>(
            (const _Float16*)S, vT[0], vT[1], vT[2], vT[3],
            rcs[0], rcs[1], rcs[2], rcs[3], h0, hcnt, Z);
    }

    final_mfma<<<dim3(32, 2, KS), blk5, 0, stream>>>(
        rcs[0], rcs[1], rcs[2], rcs[3], woT[0], woT[1], pbuf);
    final_combine<<<dim3(2048), blk, 0, stream>>>(pbuf, bo, out, KS);
}

// Round 6
// 595.371 us; speedup vs baseline: 1.0408x; 1.0408x over previous
//
#include <hip/hip_runtime.h>
#include <math.h>

// Phasor attention via split-fp16 MFMA (fp16x2 error-free splitting, ~fp32 accuracy).
// B=2, T=1024, D=512, H=8.
// Round 6: fragment-contiguous operand layouts; A-side global->VGPR direct
// (coalesced dwordx4, reg double-buffered); B-side LDS-staged (linear gll16,
// 32KB dbuf); round-4 one-sync-per-step schedule; 256 thr, 2 blocks/CU.

#define PI_F 3.14159274101257324f

typedef __attribute__((ext_vector_type(8))) _Float16 half8;
typedef __attribute__((ext_vector_type(4))) _Float16 half4;
typedef __attribute__((ext_vector_type(2))) _Float16 half2v;
typedef __attribute__((ext_vector_type(16))) float f32x16;
typedef unsigned int u32;

#define MFMA32(a, b, c) __builtin_amdgcn_mfma_f32_32x32x16_f16((a), (b), (c), 0, 0, 0)
// C/D layout for 32x32: col = lane&31, row = (reg&3) + 8*(reg>>2) + 4*(lane>>5)
#define ROWOF(r, ln) (((r) & 3) + 8 * ((r) >> 2) + 4 * ((ln) >> 5))

__device__ __forceinline__ void gll16(const void* g, void* l) {
    __builtin_amdgcn_global_load_lds(
        (const __attribute__((address_space(1))) u32*)g,
        (__attribute__((address_space(3))) u32*)l, 16, 0, 0);
}

__device__ __forceinline__ void split2(float x, _Float16& h, _Float16& l) {
    _Float16 hh = (_Float16)x;
    h = hh;
    l = (_Float16)((x - (float)hh) * 4096.0f);
}

// fragment-contiguous layout for an [M][K] fp16 plane:
// frag F = (m>>5)*(K/16) + (k>>4), 1KB each; lane = (m&31)+32*((k>>3)&1);
// elem offset = F*512 + lane*8 + (k&7)
__device__ __forceinline__ size_t feo(int m, int k, int Kd16) {
    return ((size_t)((m >> 5) * Kd16 + (k >> 4))) * 512
           + ((m & 31) + 32 * ((k >> 3) & 1)) * 8 + (k & 7);
}

// bijective XCD swizzle (nwg divisible by 8)
__device__ __forceinline__ int xcdswz(int bid, int nwg) {
    const int cpx = nwg >> 3;
    return (bid & 7) * cpx + (bid >> 3);
}

// ---------------------------------------------------------------------------
// encode: x [2048][512] f32 -> phasor planes cos/sin hi/lo, frag layout K=512.
// ---------------------------------------------------------------------------
__global__ __launch_bounds__(256) void encode_phasor(
    const float* __restrict__ x,
    _Float16* __restrict__ ch, _Float16* __restrict__ cl,
    _Float16* __restrict__ sh, _Float16* __restrict__ sl)
{
    const int idx = blockIdx.x * 256 + threadIdx.x;
    const int m = idx >> 7, k4 = (idx & 127) * 4;
    float4 v = ((const float4*)x)[idx];
    float cc[4], ss[4];
    sincosf(PI_F * v.x, &ss[0], &cc[0]);
    sincosf(PI_F * v.y, &ss[1], &cc[1]);
    sincosf(PI_F * v.z, &ss[2], &cc[2]);
    sincosf(PI_F * v.w, &ss[3], &cc[3]);
    half4 chv, clv, shv, slv;
#pragma unroll
    for (int q = 0; q < 4; ++q) {
        _Float16 a, b;
        split2(cc[q], a, b); chv[q] = a; clv[q] = b;
        split2(ss[q], a, b); shv[q] = a; slv[q] = b;
    }
    const size_t off = feo(m, k4, 32);
    *(half4*)(ch + off) = chv;
    *(half4*)(cl + off) = clv;
    *(half4*)(sh + off) = shv;
    *(half4*)(sl + off) = slv;
}

// ---------------------------------------------------------------------------
// tsplit64: w [h][K][N=512] f32 -> transposed split planes th/tl [h][512][K],
// fragment layout.
// ---------------------------------------------------------------------------
__global__ __launch_bounds__(256) void tsplit64(
    const float* __restrict__ w, _Float16* __restrict__ th, _Float16* __restrict__ tl,
    int K, int N)
{
    const int kt = blockIdx.x, ntile = blockIdx.y, h = blockIdx.z;
    const int k0 = kt * 64, n0 = ntile * 64;
    __shared__ float T[64][65];
    const int tid = threadIdx.x;
    const float* wb = w + (size_t)h * K * N;
    {
        const int r = tid >> 4, c4 = (tid & 15) * 4;
#pragma unroll
        for (int rr = 0; rr < 64; rr += 16) {
            float4 v = *(const float4*)&wb[(size_t)(k0 + rr + r) * N + n0 + c4];
            T[rr + r][c4 + 0] = v.x; T[rr + r][c4 + 1] = v.y;
            T[rr + r][c4 + 2] = v.z; T[rr + r][c4 + 3] = v.w;
        }
    }
    __syncthreads();
    {
        const int n = n0 + (tid >> 2), kq = k0 + (tid & 3) * 16;
        half8 hv[2], lv[2];
#pragma unroll
        for (int q = 0; q < 16; ++q) {
            float f = T[kq - k0 + q][n - n0];
            _Float16 hh, ll; split2(f, hh, ll);
            hv[q >> 3][q & 7] = hh; lv[q >> 3][q & 7] = ll;
        }
        const size_t hb = (size_t)h * 512 * K;
        const size_t offA = hb + ((size_t)((n >> 5) * (K >> 4) + (kq >> 4))) * 512
                            + (n & 31) * 8;
        *(half8*)(th + offA) = hv[0]; *(half8*)(th + offA + 256) = hv[1];
        *(half8*)(tl + offA) = lv[0]; *(half8*)(tl + offA + 256) = lv[1];
    }
}

// ---------------------------------------------------------------------------
// proj: y = phasor(x) @ w + bias -> normalize -> split phasors.
// Block 64(m) x 128(n), 4 waves (2x2), wave-tile 32x64, BK=32, NS=16.
// A (x planes, frag K=512) direct global->reg; B (wT, frag) LDS dbuf 2x16KB.
// VT=0: qz (c,s interleaved, frag M=1024,K=1024). VT=1: vT planes (frag
// M=512 d, K=1024 t) via 4-round LDS transpose.
// ---------------------------------------------------------------------------
template<bool VT>
__global__ __launch_bounds__(256, 2) void proj_mfma(
    const _Float16* __restrict__ xch, const _Float16* __restrict__ xcl,
    const _Float16* __restrict__ xsh, const _Float16* __restrict__ xsl,
    const _Float16* __restrict__ wth, const _Float16* __restrict__ wtl,
    const float* __restrict__ bias,
    _Float16* __restrict__ ozh, _Float16* __restrict__ ozl,
    _Float16* __restrict__ vc_h, _Float16* __restrict__ vc_l,
    _Float16* __restrict__ vs_h, _Float16* __restrict__ vs_l,
    int h0, int hcnt)
{
    const int m0 = blockIdx.x * 64;
    const int hc = blockIdx.y >> 2;
    const int n0 = (blockIdx.y & 3) * 128;
    __shared__ char lds[32768];
    const int tid = threadIdx.x, wv = tid >> 6, ln = tid & 63;
    const int wr = wv >> 1, wc = wv & 1, lm32 = ln & 31;

    // A pointers: frag row-tile Rm = (m0>>5)+wr, K/16 = 32
    const size_t abase = ((size_t)((m0 >> 5) + wr)) * 32 * 512 + ln * 8;
    const _Float16* pxc[2] = { xch + abase, xcl + abase };
    const _Float16* pxs[2] = { xsh + abase, xsl + abase };

    // B staging: 16 frags/step: g = jt*4 + hl*2 + ks
    const char* spB[4]; int dpB[4];
#pragma unroll
    for (int u = 0; u < 4; ++u) {
        const int g = wv * 4 + u;
        const int jt = g >> 2, hl = (g >> 1) & 1, ks = g & 1;
        const _Float16* base = (hl ? wtl : wth) + (size_t)hc * 262144;
        spB[u] = (const char*)(base
                 + ((size_t)(((n0 + jt * 32) >> 5) * 32 + ks)) * 512 + ln * 8);
        dpB[u] = g * 1024;
    }

    f32x16 ach[2] = {}, acl[2] = {}, ash[2] = {}, asl[2] = {};

    auto LOADA = [&](int s, half8 (&ac)[2][2], half8 (&as)[2][2]) {
#pragma unroll
        for (int hl = 0; hl < 2; ++hl)
#pragma unroll
            for (int ks = 0; ks < 2; ++ks) {
                ac[hl][ks] = *(const half8*)(pxc[hl] + (2 * s + ks) * 512);
                as[hl][ks] = *(const half8*)(pxs[hl] + (2 * s + ks) * 512);
            }
    };
    auto STAGEB = [&](int s, int buf) {
#pragma unroll
        for (int u = 0; u < 4; ++u)
            gll16(spB[u] + (size_t)s * 2048, lds + buf + dpB[u]);
    };
    auto MSTEP = [&](int buf, half8 (&ac)[2][2], half8 (&as)[2][2]) {
        half8 w0[2][2], w1[2][2];
#pragma unroll
        for (int ks = 0; ks < 2; ++ks)
#pragma unroll
            for (int j = 0; j < 2; ++j) {
                const int gb = (wc * 2 + j) * 4 + ks;
                w0[ks][j] = *(const half8*)(lds + buf + gb * 1024 + ln * 16);
                w1[ks][j] = *(const half8*)(lds + buf + (gb + 2) * 1024 + ln * 16);
            }
        __builtin_amdgcn_s_setprio(1);
#pragma unroll
        for (int ks = 0; ks < 2; ++ks)
#pragma unroll
            for (int j = 0; j < 2; ++j) {
                ach[j] = MFMA32(ac[0][ks], w0[ks][j], ach[j]);
                acl[j] = MFMA32(ac[0][ks], w1[ks][j], acl[j]);
                acl[j] = MFMA32(ac[1][ks], w0[ks][j], acl[j]);
                ash[j] = MFMA32(as[0][ks], w0[ks][j], ash[j]);
                asl[j] = MFMA32(as[0][ks], w1[ks][j], asl[j]);
                asl[j] = MFMA32(as[1][ks], w0[ks][j], asl[j]);
            }
        __builtin_amdgcn_s_setprio(0);
    };

    half8 Ac0[2][2], As0[2][2], Ac1[2][2], As1[2][2];
    LOADA(0, Ac0, As0); STAGEB(0, 0);
    const int NS = 16;
    for (int s = 0; s < NS; s += 2) {
        __syncthreads();
        STAGEB(s + 1, 16384); LOADA(s + 1, Ac1, As1);
        MSTEP(0, Ac0, As0);
        __syncthreads();
        if (s + 2 < NS) { STAGEB(s + 2, 0); LOADA(s + 2, Ac0, As0); }
        MSTEP(16384, Ac1, As1);
    }

    const float LS = 1.0f / 4096.0f;
    const int b = m0 >> 10, tbase = m0 & 1023;
    const size_t zz = (size_t)(b * hcnt + hc);
    if constexpr (!VT) {
        const size_t zb = zz << 20;
#pragma unroll
        for (int j = 0; j < 2; ++j) {
            const int nloc = wc * 64 + j * 32 + lm32;
            const float bval = bias[(size_t)(h0 + hc) * 512 + n0 + nloc];
            const int kk = 2 * (n0 + nloc);
#pragma unroll
            for (int r = 0; r < 16; ++r) {
                const int mloc = wr * 32 + ROWOF(r, ln);
                float yc = ach[j][r] + acl[j][r] * LS + bval;
                float ys = ash[j][r] + asl[j][r] * LS;
                float inv = 1.0f / sqrtf(fmaxf(yc * yc + ys * ys, 1e-36f));
                float c = yc * inv, sn = ys * inv;
                _Float16 chh, chl, shh, shl;
                split2(c, chh, chl); split2(sn, shh, shl);
                const size_t off = zb + feo(tbase + mloc, kk, 64);
                half2v hv, lv;
                hv[0] = chh; hv[1] = shh; lv[0] = chl; lv[1] = shl;
                *(half2v*)(ozh + off) = hv;
                *(half2v*)(ozl + off) = lv;
            }
        }
    } else {
        // compute all 4 plane values, then 4 LDS-transpose rounds (18.4KB each)
        _Float16 vh[4][2][16];
#pragma unroll
        for (int j = 0; j < 2; ++j) {
            const int nloc = wc * 64 + j * 32 + lm32;
            const float bval = bias[(size_t)(h0 + hc) * 512 + n0 + nloc];
#pragma unroll
            for (int r = 0; r < 16; ++r) {
                float yc = ach[j][r] + acl[j][r] * LS + bval;
                float ys = ash[j][r] + asl[j][r] * LS;
                float inv = 1.0f / sqrtf(fmaxf(yc * yc + ys * ys, 1e-36f));
                _Float16 a, bq_;
                split2(yc * inv, a, bq_); vh[0][j][r] = a; vh[1][j][r] = bq_;
                split2(ys * inv, a, bq_); vh[2][j][r] = a; vh[3][j][r] = bq_;
            }
        }
        const size_t zvb = zz * 524288;
        _Float16* outp[4] = { vc_h, vc_l, vs_h, vs_l };
#pragma unroll
        for (int p = 0; p < 4; ++p) {
            __syncthreads();
            _Float16* T = (_Float16*)lds;
#pragma unroll
            for (int j = 0; j < 2; ++j) {
                const int dloc = wc * 64 + j * 32 + lm32;
#pragma unroll
                for (int r = 0; r < 16; ++r)
                    T[dloc * 72 + wr * 32 + ROWOF(r, ln)] = vh[p][j][r];
            }
            __syncthreads();
            const int d_l = tid >> 1, seg = tid & 1;
            const int dg = n0 + d_l;
#pragma unroll
            for (int q = 0; q < 4; ++q) {
                const int tg = tbase + seg * 32 + q * 8;
                const size_t off = zvb + feo(dg, tg, 64);
                *(half8*)(outp[p] + off) = *(const half8*)(T + d_l * 72 + seg * 32 + q * 8);
            }
        }
    }
}

// ---------------------------------------------------------------------------
// scores: S[z][t][T] = (qz . kz)/512, K=1024 (c,s interleaved, frag layout).
// Block 128x128, waves 2x2, wave-tile 64x64, BK=32, NS=32. A direct, B LDS.
// ---------------------------------------------------------------------------
__global__ __launch_bounds__(256, 2) void scores_mfma(
    const _Float16* __restrict__ qzh, const _Float16* __restrict__ qzl,
    const _Float16* __restrict__ kzh, const _Float16* __restrict__ kzl,
    float* __restrict__ S, int Z)
{
    const int wg = xcdswz(blockIdx.x, Z * 64);
    const int z = wg >> 6;
    const int rem = wg & 63;
    const int m0 = (rem & 7) << 7, n0 = (rem >> 3) << 7;
    __shared__ char lds[32768];
    const size_t zb = (size_t)z << 20;
    const int tid = threadIdx.x, wv = tid >> 6, ln = tid & 63;
    const int wr = wv >> 1, wc = wv & 1, lm32 = ln & 31;

    const _Float16* pa[2] = { qzh + zb + ln * 8, qzl + zb + ln * 8 };
    const char* spB[4]; int dpB[4];
#pragma unroll
    for (int u = 0; u < 4; ++u) {
        const int g = wv * 4 + u;
        const int jt = g >> 2, hl = (g >> 1) & 1, ks = g & 1;
        spB[u] = (const char*)((hl ? kzl : kzh) + zb
                 + ((size_t)(((n0 + jt * 32) >> 5) * 64 + ks)) * 512 + ln * 8);
        dpB[u] = g * 1024;
    }

    f32x16 acch[2][2] = {}, accl[2][2] = {};

    auto LOADA = [&](int s, half8 (&a)[2][2][2]) {   // [hl][i][ks]
#pragma unroll
        for (int hl = 0; hl < 2; ++hl)
#pragma unroll
            for (int i = 0; i < 2; ++i)
#pragma unroll
                for (int ks = 0; ks < 2; ++ks)
                    a[hl][i][ks] = *(const half8*)(pa[hl]
                        + ((size_t)((m0 >> 5) + wr * 2 + i) * 64 + 2 * s + ks) * 512);
    };
    auto STAGEB = [&](int s, int buf) {
#pragma unroll
        for (int u = 0; u < 4; ++u)
            gll16(spB[u] + (size_t)s * 2048, lds + buf + dpB[u]);
    };
    auto MSTEP = [&](int buf, half8 (&a)[2][2][2]) {
        half8 bh[2][2], bl[2][2];
#pragma unroll
        for (int ks = 0; ks < 2; ++ks)
#pragma unroll
            for (int j = 0; j < 2; ++j) {
                const int gb = (wc * 2 + j) * 4 + ks;
                bh[ks][j] = *(const half8*)(lds + buf + gb * 1024 + ln * 16);
                bl[ks][j] = *(const half8*)(lds + buf + (gb + 2) * 1024 + ln * 16);
            }
        __builtin_amdgcn_s_setprio(1);
#pragma unroll
        for (int ks = 0; ks < 2; ++ks)
#pragma unroll
            for (int i = 0; i < 2; ++i)
#pragma unroll
                for (int j = 0; j < 2; ++j) {
                    acch[i][j] = MFMA32(a[0][i][ks], bh[ks][j], acch[i][j]);
                    accl[i][j] = MFMA32(a[0][i][ks], bl[ks][j], accl[i][j]);
                    accl[i][j] = MFMA32(a[1][i][ks], bh[ks][j], accl[i][j]);
                }
        __builtin_amdgcn_s_setprio(0);
    };

    half8 A0[2][2][2], A1[2][2][2];
    LOADA(0, A0); STAGEB(0, 0);
    const int NS = 32;
    for (int s = 0; s < NS; s += 2) {
        __syncthreads();
        STAGEB(s + 1, 16384); LOADA(s + 1, A1);
        MSTEP(0, A0);
        __syncthreads();
        if (s + 2 < NS) { STAGEB(s + 2, 0); LOADA(s + 2, A0); }
        MSTEP(16384, A1);
    }
    const float LS = 1.0f / 4096.0f, SC = 1.0f / 512.0f;
#pragma unroll
    for (int i = 0; i < 2; ++i)
#pragma unroll
        for (int j = 0; j < 2; ++j)
#pragma unroll
            for (int r = 0; r < 16; ++r) {
                const int row = m0 + wr * 64 + i * 32 + ROWOF(r, ln);
                const int col = n0 + wc * 64 + j * 32 + lm32;
                S[zb + (size_t)row * 1024 + col] =
                    (acch[i][j][r] + accl[i][j][r] * LS) * SC;
            }
}

// ---------------------------------------------------------------------------
// softmax rows of 1024; write P hi/lo planes in pv-A frag layout (M=1024,K=1024).
// ---------------------------------------------------------------------------
__global__ __launch_bounds__(256) void softmax_split(
    const float* __restrict__ S, _Float16* __restrict__ Ph, _Float16* __restrict__ Pl)
{
    const int z = blockIdx.x >> 10, t = blockIdx.x & 1023;
    const float* p = S + ((size_t)blockIdx.x << 10);
    const int tid = threadIdx.x;
    float4 v = ((const float4*)p)[tid];
    float m = fmaxf(fmaxf(v.x, v.y), fmaxf(v.z, v.w));
#pragma unroll
    for (int off = 32; off >= 1; off >>= 1)
        m = fmaxf(m, __shfl_xor(m, off));
    __shared__ float redm[4], reds[4];
    const int wid = tid >> 6, lane = tid & 63;
    if (lane == 0) redm[wid] = m;
    __syncthreads();
    m = fmaxf(fmaxf(redm[0], redm[1]), fmaxf(redm[2], redm[3]));
    float4 e;
    e.x = expf(v.x - m); e.y = expf(v.y - m);
    e.z = expf(v.z - m); e.w = expf(v.w - m);
    float s = (e.x + e.y) + (e.z + e.w);
#pragma unroll
    for (int off = 32; off >= 1; off >>= 1)
        s += __shfl_xor(s, off);
    if (lane == 0) reds[wid] = s;
    __syncthreads();
    s = (reds[0] + reds[1]) + (reds[2] + reds[3]);
    e.x /= s; e.y /= s; e.z /= s; e.w /= s;
    half4 hv, lv;
    _Float16 a, b;
    split2(e.x, a, b); hv[0] = a; lv[0] = b;
    split2(e.y, a, b); hv[1] = a; lv[1] = b;
    split2(e.z, a, b); hv[2] = a; lv[2] = b;
    split2(e.w, a, b); hv[3] = a; lv[3] = b;
    const size_t off = ((size_t)z << 20) + feo(t, tid * 4, 64);
    *(half4*)(Ph + off) = hv;
    *(half4*)(Pl + off) = lv;
}

// ---------------------------------------------------------------------------
// pv: out[z][t][d] = sum_T P[t][T]*vz[T][d], normalize, split -> rcs planes
// (frag M=2048, K=4096). Block 128(t)x64(d), waves 2x2, wave-tile 64x32, NS=32.
// ---------------------------------------------------------------------------
__global__ __launch_bounds__(256, 2) void pv_mfma(
    const _Float16* __restrict__ Ph, const _Float16* __restrict__ Pl,
    const _Float16* __restrict__ vch, const _Float16* __restrict__ vcl,
    const _Float16* __restrict__ vsh, const _Float16* __restrict__ vsl,
    _Float16* __restrict__ rch, _Float16* __restrict__ rcl,
    _Float16* __restrict__ rsh, _Float16* __restrict__ rsl,
    int h0, int hcnt, int Z)
{
    const int wg = xcdswz(blockIdx.x, Z * 64);
    const int z = wg >> 6;
    const int rem = wg & 63;
    const int m0 = (rem & 7) << 7, n0 = (rem >> 3) << 6;
    __shared__ char lds[32768];
    const int tid = threadIdx.x, wv = tid >> 6, ln = tid & 63;
    const int wr = wv >> 1, wc = wv & 1, lm32 = ln & 31;

    const size_t zb = (size_t)z << 20, zvb = (size_t)z * 524288;
    const _Float16* pa[2] = { Ph + zb + ln * 8, Pl + zb + ln * 8 };
    // B frags: g = pl*8 + dt*4 + hl*2 + ks  (pl: 0=c 1=s)
    const char* spB[4]; int dpB[4];
#pragma unroll
    for (int u = 0; u < 4; ++u) {
        const int g = wv * 4 + u;
        const int pl = g >> 3, dt = (g >> 2) & 1, hl = (g >> 1) & 1, ks = g & 1;
        const _Float16* base = pl ? (hl ? vsl : vsh) : (hl ? vcl : vch);
        spB[u] = (const char*)(base + zvb
                 + ((size_t)(((n0 + dt * 32) >> 5) * 64 + ks)) * 512 + ln * 8);
        dpB[u] = g * 1024;
    }

    f32x16 ac_h[2] = {}, ac_l[2] = {}, as_h[2] = {}, as_l[2] = {};

    auto LOADA = [&](int s, half8 (&a)[2][2][2]) {   // [hl][i][ks]
#pragma unroll
        for (int hl = 0; hl < 2; ++hl)
#pragma unroll
            for (int i = 0; i < 2; ++i)
#pragma unroll
                for (int ks = 0; ks < 2; ++ks)
                    a[hl][i][ks] = *(const half8*)(pa[hl]
                        + ((size_t)((m0 >> 5) + wr * 2 + i) * 64 + 2 * s + ks) * 512);
    };
    auto STAGEB = [&](int s, int buf) {
#pragma unroll
        for (int u = 0; u < 4; ++u)
            gll16(spB[u] + (size_t)s * 2048, lds + buf + dpB[u]);
    };
    auto MSTEP = [&](int buf, half8 (&a)[2][2][2]) {
        half8 vc[2][2], vs[2][2];   // [hl][ks]
#pragma unroll
        for (int hl = 0; hl < 2; ++hl)
#pragma unroll
            for (int ks = 0; ks < 2; ++ks) {
                vc[hl][ks] = *(const half8*)(lds + buf + (wc * 4 + hl * 2 + ks) * 1024 + ln * 16);
                vs[hl][ks] = *(const half8*)(lds + buf + (8 + wc * 4 + hl * 2 + ks) * 1024 + ln * 16);
            }
        __builtin_amdgcn_s_setprio(1);
#pragma unroll
        for (int ks = 0; ks < 2; ++ks)
#pragma unroll
            for (int i = 0; i < 2; ++i) {
                ac_h[i] = MFMA32(a[0][i][ks], vc[0][ks], ac_h[i]);
                ac_l[i] = MFMA32(a[0][i][ks], vc[1][ks], ac_l[i]);
                ac_l[i] = MFMA32(a[1][i][ks], vc[0][ks], ac_l[i]);
                as_h[i] = MFMA32(a[0][i][ks], vs[0][ks], as_h[i]);
                as_l[i] = MFMA32(a[0][i][ks], vs[1][ks], as_l[i]);
                as_l[i] = MFMA32(a[1][i][ks], vs[0][ks], as_l[i]);
            }
        __builtin_amdgcn_s_setprio(0);
    };

    half8 A0[2][2][2], A1[2][2][2];
    LOADA(0, A0); STAGEB(0, 0);
    const int NS = 32;
    for (int s = 0; s < NS; s += 2) {
        __syncthreads();
        STAGEB(s + 1, 16384); LOADA(s + 1, A1);
        MSTEP(0, A0);
        __syncthreads();
        if (s + 2 < NS) { STAGEB(s + 2, 0); LOADA(s + 2, A0); }
        MSTEP(16384, A1);
    }
    const float LS = 1.0f / 4096.0f;
    const int b = z / hcnt, hg = h0 + z % hcnt;
#pragma unroll
    for (int i = 0; i < 2; ++i)
#pragma unroll
        for (int r = 0; r < 16; ++r) {
            const int t = m0 + wr * 64 + i * 32 + ROWOF(r, ln);
            const int d = n0 + wc * 32 + lm32;
            float zc = ac_h[i][r] + ac_l[i][r] * LS;
            float zs = as_h[i][r] + as_l[i][r] * LS;
            float inv = 1.0f / sqrtf(fmaxf(zc * zc + zs * zs, 1e-36f));
            _Float16 chh, chl, shh, shl;
            split2(zc * inv, chh, chl);
            split2(zs * inv, shh, shl);
            const size_t off = feo(b * 1024 + t, hg * 512 + d, 256);
            rch[off] = chh; rcl[off] = chl; rsh[off] = shh; rsl[off] = shl;
        }
}

// ---------------------------------------------------------------------------
// final (K-split): partial z = rz @ wo over K range [kspl*1024, +1024).
// Block 64(m)x128(n), waves 2x2, wave-tile 32x64, NS=32. Writes f32 (zr,zi).
// ---------------------------------------------------------------------------
__global__ __launch_bounds__(256, 2) void final_mfma(
    const _Float16* __restrict__ rch, const _Float16* __restrict__ rcl,
    const _Float16* __restrict__ rsh, const _Float16* __restrict__ rsl,
    const _Float16* __restrict__ woh, const _Float16* __restrict__ wol,
    float* __restrict__ pbuf)
{
    const int m0 = blockIdx.x * 64, n0 = blockIdx.y * 128;
    const int kspl = blockIdx.z;
    const int kf = kspl * 64;   // frag-column base (1024/16)
    __shared__ char lds[32768];
    const int tid = threadIdx.x, wv = tid >> 6, ln = tid & 63;
    const int wr = wv >> 1, wc = wv & 1, lm32 = ln & 31;

    const size_t abase = ((size_t)((m0 >> 5) + wr) * 256 + kf) * 512 + ln * 8;
    const _Float16* prc[2] = { rch + abase, rcl + abase };
    const _Float16* prs[2] = { rsh + abase, rsl + abase };
    const char* spB[4]; int dpB[4];
#pragma unroll
    for (int u = 0; u < 4; ++u) {
        const int g = wv * 4 + u;
        const int jt = g >> 2, hl = (g >> 1) & 1, ks = g & 1;
        spB[u] = (const char*)((hl ? wol : woh)
                 + ((size_t)(((n0 + jt * 32) >> 5) * 256 + kf + ks)) * 512 + ln * 8);
        dpB[u] = g * 1024;
    }

    f32x16 rr_h[2] = {}, rr_l[2] = {}, ri_h[2] = {}, ri_l[2] = {};

    auto LOADA = [&](int s, half8 (&ac)[2][2], half8 (&as)[2][2]) {
#pragma unroll
        for (int hl = 0; hl < 2; ++hl)
#pragma unroll
            for (int ks = 0; ks < 2; ++ks) {
                ac[hl][ks] = *(const half8*)(prc[hl] + (2 * s + ks) * 512);
                as[hl][ks] = *(const half8*)(prs[hl] + (2 * s + ks) * 512);
            }
    };
    auto STAGEB = [&](int s, int buf) {
#pragma unroll
        for (int u = 0; u < 4; ++u)
            gll16(spB[u] + (size_t)s * 2048, lds + buf + dpB[u]);
    };
    auto MSTEP = [&](int buf, half8 (&ac)[2][2], half8 (&as)[2][2]) {
        half8 w0[2][2], w1[2][2];
#pragma unroll
        for (int ks = 0; ks < 2; ++ks)
#pragma unroll
            for (int j = 0; j < 2; ++j) {
                const int gb = (wc * 2 + j) * 4 + ks;
                w0[ks][j] = *(const half8*)(lds + buf + gb * 1024 + ln * 16);
                w1[ks][j] = *(const half8*)(lds + buf + (gb + 2) * 1024 + ln * 16);
            }
        __builtin_amdgcn_s_setprio(1);
#pragma unroll
        for (int ks = 0; ks < 2; ++ks)
#pragma unroll
            for (int j = 0; j < 2; ++j) {
                rr_h[j] = MFMA32(ac[0][ks], w0[ks][j], rr_h[j]);
                rr_l[j] = MFMA32(ac[0][ks], w1[ks][j], rr_l[j]);
                rr_l[j] = MFMA32(ac[1][ks], w0[ks][j], rr_l[j]);
                ri_h[j] = MFMA32(as[0][ks], w0[ks][j], ri_h[j]);
                ri_l[j] = MFMA32(as[0][ks], w1[ks][j], ri_l[j]);
                ri_l[j] = MFMA32(as[1][ks], w0[ks][j], ri_l[j]);
            }
        __builtin_amdgcn_s_setprio(0);
    };

    half8 Ac0[2][2], As0[2][2], Ac1[2][2], As1[2][2];
    LOADA(0, Ac0, As0); STAGEB(0, 0);
    const int NS = 32;
    for (int s = 0; s < NS; s += 2) {
        __syncthreads();
        STAGEB(s + 1, 16384); LOADA(s + 1, Ac1, As1);
        MSTEP(0, Ac0, As0);
        __syncthreads();
        if (s + 2 < NS) { STAGEB(s + 2, 0); LOADA(s + 2, Ac0, As0); }
        MSTEP(16384, Ac1, As1);
    }
    const float LS = 1.0f / 4096.0f;
#pragma unroll
    for (int j = 0; j < 2; ++j) {
        const int ng = n0 + wc * 64 + j * 32 + lm32;
#pragma unroll
        for (int r = 0; r < 16; ++r) {
            const int mg = m0 + wr * 32 + ROWOF(r, ln);
            float2 v;
            v.x = rr_h[j][r] + rr_l[j][r] * LS;
            v.y = ri_h[j][r] + ri_l[j][r] * LS;
            *(float2*)&pbuf[((size_t)(kspl * 2048 + mg) * 512 + ng) * 2] = v;
        }
    }
}

// ---------------------------------------------------------------------------
// combine: out[m][n] = atan2(sum zi, sum zr + bo[n]) / pi
// ---------------------------------------------------------------------------
__global__ __launch_bounds__(256) void final_combine(
    const float* __restrict__ pbuf, const float* __restrict__ bo,
    float* __restrict__ out, int KS)
{
    const int m = blockIdx.x, t = threadIdx.x;
    float4 acc = {0.f, 0.f, 0.f, 0.f};
    for (int s = 0; s < KS; ++s) {
        float4 v = *(const float4*)&pbuf[(size_t)(s * 2048 + m) * 1024 + t * 4];
        acc.x += v.x; acc.y += v.y; acc.z += v.z; acc.w += v.w;
    }
    const int n0 = t * 2;
    out[(size_t)m * 512 + n0]     = atan2f(acc.y, acc.x + bo[n0]) / PI_F;
    out[(size_t)m * 512 + n0 + 1] = atan2f(acc.w, acc.z + bo[n0 + 1]) / PI_F;
}

// ---------------------------------------------------------------------------
extern "C" void kernel_launch(void* const* d_in, const int* in_sizes, int n_in,
                              void* d_out, int out_size, void* d_ws, size_t ws_size,
                              hipStream_t stream)
{
    (void)in_sizes; (void)n_in; (void)out_size;
    const float* query    = (const float*)d_in[0];
    const float* keyvalue = (const float*)d_in[1];
    const float* wq = (const float*)d_in[2];
    const float* bq = (const float*)d_in[3];
    const float* wk = (const float*)d_in[4];
    const float* bk = (const float*)d_in[5];
    const float* wv = (const float*)d_in[6];
    const float* bv = (const float*)d_in[7];
    const float* wo = (const float*)d_in[8];
    const float* bo = (const float*)d_in[9];
    float* out = (float*)d_out;

    int hcnt;
    if (ws_size >= (size_t)320 * 1024 * 1024) hcnt = 8;
    else if (ws_size >= (size_t)240 * 1024 * 1024) hcnt = 4;
    else hcnt = 2;
    const int Z = 2 * hcnt;
    const int KS = (hcnt == 2) ? 2 : 4;

    char* p = (char*)d_ws;
    auto alloc = [&](size_t bytes) {
        char* r = p;
        p += (bytes + 255) & ~(size_t)255;
        return r;
    };
    const size_t PLX = (size_t)2048 * 512;
    _Float16* xq[4]; for (int i = 0; i < 4; ++i) xq[i] = (_Float16*)alloc(PLX * 2);
    _Float16* xk[4]; for (int i = 0; i < 4; ++i) xk[i] = (_Float16*)alloc(PLX * 2);
    _Float16* woT[2]; for (int i = 0; i < 2; ++i) woT[i] = (_Float16*)alloc((size_t)512 * 4096 * 2);
    const size_t WTE = (size_t)hcnt * 512 * 512;
    _Float16* wqT[2]; for (int i = 0; i < 2; ++i) wqT[i] = (_Float16*)alloc(WTE * 2);
    _Float16* wkT[2]; for (int i = 0; i < 2; ++i) wkT[i] = (_Float16*)alloc(WTE * 2);
    _Float16* wvT[2]; for (int i = 0; i < 2; ++i) wvT[i] = (_Float16*)alloc(WTE * 2);
    const size_t QZE = (size_t)Z * 1024 * 1024;
    _Float16* qz[2]; for (int i = 0; i < 2; ++i) qz[i] = (_Float16*)alloc(QZE * 2);
    _Float16* kz[2]; for (int i = 0; i < 2; ++i) kz[i] = (_Float16*)alloc(QZE * 2);
    float* S = (float*)alloc(QZE * 4);
    const size_t VTE = (size_t)Z * 512 * 1024;
    _Float16* vT[4]; for (int i = 0; i < 4; ++i) vT[i] = (_Float16*)alloc(VTE * 2);
    const size_t RCE = (size_t)2048 * 4096;
    _Float16* rcs[4];
    if (hcnt == 8) {
        // overlay on qz (dead after scores; single chunk)
        for (int i = 0; i < 4; ++i) rcs[i] = (_Float16*)((char*)qz[0] + (size_t)i * RCE * 2);
    } else {
        for (int i = 0; i < 4; ++i) rcs[i] = (_Float16*)alloc(RCE * 2);
    }
    // P hi/lo planes overlay kz (dead after scores); pbuf overlays kz too
    // (written by final_mfma only after pv has consumed P).
    _Float16* Ph = kz[0];
    _Float16* Pl = kz[1];
    float* pbuf = (float*)kz[0];

    dim3 blk(256);

    encode_phasor<<<1024, blk, 0, stream>>>(query, xq[0], xq[1], xq[2], xq[3]);
    encode_phasor<<<1024, blk, 0, stream>>>(keyvalue, xk[0], xk[1], xk[2], xk[3]);
    tsplit64<<<dim3(64, 8, 1), blk, 0, stream>>>(wo, woT[0], woT[1], 4096, 512);

    for (int c = 0; c < 8 / hcnt; ++c) {
        const int h0 = c * hcnt;
        const float* wqc = wq + (size_t)h0 * 512 * 512;
        const float* wkc = wk + (size_t)h0 * 512 * 512;
        const float* wvc = wv + (size_t)h0 * 512 * 512;
        tsplit64<<<dim3(8, 8, hcnt), blk, 0, stream>>>(wqc, wqT[0], wqT[1], 512, 512);
        tsplit64<<<dim3(8, 8, hcnt), blk, 0, stream>>>(wkc, wkT[0], wkT[1], 512, 512);
        tsplit64<<<dim3(8, 8, hcnt), blk, 0, stream>>>(wvc, wvT[0], wvT[1], 512, 512);

        proj_mfma<false><<<dim3(32, hcnt * 4), blk, 0, stream>>>(
            xq[0], xq[1], xq[2], xq[3], wqT[0], wqT[1], bq,
            qz[0], qz[1], nullptr, nullptr, nullptr, nullptr, h0, hcnt);
        proj_mfma<false><<<dim3(32, hcnt * 4), blk, 0, stream>>>(
            xk[0], xk[1], xk[2], xk[3], wkT[0], wkT[1], bk,
            kz[0], kz[1], nullptr, nullptr, nullptr, nullptr, h0, hcnt);
        proj_mfma<true><<<dim3(32, hcnt * 4), blk, 0, stream>>>(
            xk[0], xk[1], xk[2], xk[3], wvT[0], wvT[1], bv,
            nullptr, nullptr, vT[0], vT[1], vT[2], vT[3], h0, hcnt);

        scores_mfma<<<dim3(Z * 64), blk, 0, stream>>>(qz[0], qz[1], kz[0], kz[1], S, Z);
        softmax_split<<<dim3(Z * 1024), blk, 0, stream>>>(S, Ph, Pl);
        pv_mfma<<<dim3(Z * 64), blk, 0, stream>>>(
            Ph, Pl, vT[0], vT[1], vT[2], vT[3],
            rcs[0], rcs[1], rcs[2], rcs[3], h0, hcnt, Z);
    }

    final_mfma<<<dim3(32, 4, KS), blk, 0, stream>>>(
        rcs[0], rcs[1], rcs[2], rcs[3], woT[0], woT[1], pbuf);
    final_combine<<<dim3(2048), blk, 0, stream>>>(pbuf, bo, out, KS);
}

// Round 7
// 587.127 us; speedup vs baseline: 1.0554x; 1.0140x over previous
//
#include <hip/hip_runtime.h>
#include <math.h>

// Phasor attention via split-fp16 MFMA (fp16x2 error-free splitting, ~fp32 accuracy).
// B=2, T=1024, D=512, H=8.
// Round 7: GEMM loops unchanged from r6 (63% of MFMA ceiling). All producers now
// write fragment-contiguous tensors via LDS repack with coalesced 16B stores:
// new 32-row softmax (no max-sub: |S|<=2), new encode, pv/proj epilogue repack.
// Launch fusion: encode x1, tsplit-qkv x1, proj q+k merged.

#define PI_F 3.14159274101257324f

typedef __attribute__((ext_vector_type(8))) _Float16 half8;
typedef __attribute__((ext_vector_type(4))) _Float16 half4;
typedef __attribute__((ext_vector_type(2))) _Float16 half2v;
typedef __attribute__((ext_vector_type(16))) float f32x16;
typedef unsigned int u32;

#define MFMA32(a, b, c) __builtin_amdgcn_mfma_f32_32x32x16_f16((a), (b), (c), 0, 0, 0)
// C/D layout for 32x32: col = lane&31, row = (reg&3) + 8*(reg>>2) + 4*(lane>>5)
#define ROWOF(r, ln) (((r) & 3) + 8 * ((r) >> 2) + 4 * ((ln) >> 5))

__device__ __forceinline__ void gll16(const void* g, void* l) {
    __builtin_amdgcn_global_load_lds(
        (const __attribute__((address_space(1))) u32*)g,
        (__attribute__((address_space(3))) u32*)l, 16, 0, 0);
}

__device__ __forceinline__ void split2(float x, _Float16& h, _Float16& l) {
    _Float16 hh = (_Float16)x;
    h = hh;
    l = (_Float16)((x - (float)hh) * 4096.0f);
}

// bijective XCD swizzle (nwg divisible by 8)
__device__ __forceinline__ int xcdswz(int bid, int nwg) {
    const int cpx = nwg >> 3;
    return (bid & 7) * cpx + (bid >> 3);
}

// ---------------------------------------------------------------------------
// encode: x [2048][512] f32 -> 4 phasor planes, frag layout (K=512, Kd16=32).
// Grid (64 row-tiles, 2 col-halves, 2 inputs). Coalesced 16B frag writes.
// ---------------------------------------------------------------------------
__global__ __launch_bounds__(256) void encode_phasor(
    const float* __restrict__ xq, const float* __restrict__ xkv,
    _Float16* __restrict__ qch, _Float16* __restrict__ qcl,
    _Float16* __restrict__ qsh, _Float16* __restrict__ qsl,
    _Float16* __restrict__ kch, _Float16* __restrict__ kcl,
    _Float16* __restrict__ ksh, _Float16* __restrict__ ksl)
{
    const int mt = blockIdx.x, yh = blockIdx.y, zi = blockIdx.z;
    const float* x = zi ? xkv : xq;
    __shared__ char fb[32768];
    const int tid = threadIdx.x;
    const int row = tid >> 3, lc = tid & 7;
    const float* xr = x + (size_t)(mt * 32 + row) * 512 + yh * 256;
    for (int c = 0; c < 2; ++c) {
        if (c) __syncthreads();
        half8 hs[4][2];
#pragma unroll
        for (int g = 0; g < 2; ++g)
#pragma unroll
            for (int q = 0; q < 2; ++q) {
                float4 v = *(const float4*)(xr + c * 128 + lc * 16 + g * 8 + q * 4);
                float cc[4], ss[4];
                sincosf(PI_F * v.x, &ss[0], &cc[0]);
                sincosf(PI_F * v.y, &ss[1], &cc[1]);
                sincosf(PI_F * v.z, &ss[2], &cc[2]);
                sincosf(PI_F * v.w, &ss[3], &cc[3]);
#pragma unroll
                for (int e = 0; e < 4; ++e) {
                    _Float16 a, b;
                    split2(cc[e], a, b); hs[0][g][q * 4 + e] = a; hs[1][g][q * 4 + e] = b;
                    split2(ss[e], a, b); hs[2][g][q * 4 + e] = a; hs[3][g][q * 4 + e] = b;
                }
            }
#pragma unroll
        for (int p = 0; p < 4; ++p) {
            char* base = fb + p * 8192 + lc * 1024 + row * 16;
            *(half8*)(base) = hs[p][0];
            *(half8*)(base + 512) = hs[p][1];
        }
        __syncthreads();
#pragma unroll
        for (int w = 0; w < 8; ++w) {
            const int u = w * 256 + tid;
            const int p = u >> 9, rest = u & 511;
            const int f = rest >> 6, within = rest & 63;
            _Float16* op;
            if (zi) op = (p == 0) ? kch : (p == 1) ? kcl : (p == 2) ? ksh : ksl;
            else    op = (p == 0) ? qch : (p == 1) ? qcl : (p == 2) ? qsh : qsl;
            const size_t fragG = (size_t)mt * 32 + yh * 16 + c * 8 + f;
            *(half8*)(op + fragG * 512 + within * 8) =
                *(const half8*)(fb + p * 8192 + f * 1024 + within * 16);
        }
    }
}

// ---------------------------------------------------------------------------
// tsplit64: w [h][K][N=512] f32 -> transposed split planes [h][512][K], frag.
// (writes already coalesced 512B-segment half8s)
// ---------------------------------------------------------------------------
__global__ __launch_bounds__(256) void tsplit64(
    const float* __restrict__ w, _Float16* __restrict__ th, _Float16* __restrict__ tl,
    int K, int N)
{
    const int kt = blockIdx.x, ntile = blockIdx.y, h = blockIdx.z;
    const int k0 = kt * 64, n0 = ntile * 64;
    __shared__ float T[64][65];
    const int tid = threadIdx.x;
    const float* wb = w + (size_t)h * K * N;
    {
        const int r = tid >> 4, c4 = (tid & 15) * 4;
#pragma unroll
        for (int rr = 0; rr < 64; rr += 16) {
            float4 v = *(const float4*)&wb[(size_t)(k0 + rr + r) * N + n0 + c4];
            T[rr + r][c4 + 0] = v.x; T[rr + r][c4 + 1] = v.y;
            T[rr + r][c4 + 2] = v.z; T[rr + r][c4 + 3] = v.w;
        }
    }
    __syncthreads();
    {
        const int n = n0 + (tid >> 2), kq = k0 + (tid & 3) * 16;
        half8 hv[2], lv[2];
#pragma unroll
        for (int q = 0; q < 16; ++q) {
            float f = T[kq - k0 + q][n - n0];
            _Float16 hh, ll; split2(f, hh, ll);
            hv[q >> 3][q & 7] = hh; lv[q >> 3][q & 7] = ll;
        }
        const size_t hb = (size_t)h * 512 * K;
        const size_t offA = hb + ((size_t)((n >> 5) * (K >> 4) + (kq >> 4))) * 512
                            + (n & 31) * 8;
        *(half8*)(th + offA) = hv[0]; *(half8*)(th + offA + 256) = hv[1];
        *(half8*)(tl + offA) = lv[0]; *(half8*)(tl + offA + 256) = lv[1];
    }
}

// tsplit_qkv: 3 weight tensors in one launch. Grid (8,8,3*hcnt).
__global__ __launch_bounds__(256) void tsplit_qkv(
    const float* __restrict__ wq, const float* __restrict__ wk,
    const float* __restrict__ wv,
    _Float16* __restrict__ qh, _Float16* __restrict__ ql,
    _Float16* __restrict__ kh, _Float16* __restrict__ kl,
    _Float16* __restrict__ vh, _Float16* __restrict__ vl, int hcnt)
{
    const int tsel = blockIdx.z / hcnt, h = blockIdx.z % hcnt;
    const int kt = blockIdx.x, ntile = blockIdx.y;
    const int k0 = kt * 64, n0 = ntile * 64;
    const float* w = (tsel == 0) ? wq : (tsel == 1) ? wk : wv;
    _Float16* th = (tsel == 0) ? qh : (tsel == 1) ? kh : vh;
    _Float16* tl = (tsel == 0) ? ql : (tsel == 1) ? kl : vl;
    __shared__ float T[64][65];
    const int tid = threadIdx.x;
    const float* wb = w + (size_t)h * 262144;
    {
        const int r = tid >> 4, c4 = (tid & 15) * 4;
#pragma unroll
        for (int rr = 0; rr < 64; rr += 16) {
            float4 v = *(const float4*)&wb[(size_t)(k0 + rr + r) * 512 + n0 + c4];
            T[rr + r][c4 + 0] = v.x; T[rr + r][c4 + 1] = v.y;
            T[rr + r][c4 + 2] = v.z; T[rr + r][c4 + 3] = v.w;
        }
    }
    __syncthreads();
    {
        const int n = n0 + (tid >> 2), kq = k0 + (tid & 3) * 16;
        half8 hv[2], lv[2];
#pragma unroll
        for (int q = 0; q < 16; ++q) {
            float f = T[kq - k0 + q][n - n0];
            _Float16 hh, ll; split2(f, hh, ll);
            hv[q >> 3][q & 7] = hh; lv[q >> 3][q & 7] = ll;
        }
        const size_t hb = (size_t)h * 262144;
        const size_t offA = hb + ((size_t)((n >> 5) * 32 + (kq >> 4))) * 512 + (n & 31) * 8;
        *(half8*)(th + offA) = hv[0]; *(half8*)(th + offA + 256) = hv[1];
        *(half8*)(tl + offA) = lv[0]; *(half8*)(tl + offA + 256) = lv[1];
    }
}

// ---------------------------------------------------------------------------
// proj_qk: y = phasor(x) @ w + bias -> normalize -> qz/kz (c,s interleaved,
// frag M=1024 K=1024). Block 64x128, waves 2x2, wave-tile 32x64, BK=32, NS=16.
// A direct global->reg; B LDS dbuf 2x16KB. z: 0=query, 1=key. LDS-repack epilogue.
// ---------------------------------------------------------------------------
__global__ __launch_bounds__(256, 2) void proj_qk(
    const _Float16* __restrict__ qch, const _Float16* __restrict__ qcl,
    const _Float16* __restrict__ qsh, const _Float16* __restrict__ qsl,
    const _Float16* __restrict__ kch, const _Float16* __restrict__ kcl,
    const _Float16* __restrict__ ksh, const _Float16* __restrict__ ksl,
    const _Float16* __restrict__ wqh, const _Float16* __restrict__ wql,
    const _Float16* __restrict__ wkh, const _Float16* __restrict__ wkl,
    const float* __restrict__ bq, const float* __restrict__ bk,
    _Float16* __restrict__ qzh, _Float16* __restrict__ qzl,
    _Float16* __restrict__ kzh, _Float16* __restrict__ kzl,
    int h0, int hcnt)
{
    const int inp = blockIdx.z;
    const _Float16* xch = inp ? kch : qch;
    const _Float16* xcl = inp ? kcl : qcl;
    const _Float16* xsh = inp ? ksh : qsh;
    const _Float16* xsl = inp ? ksl : qsl;
    const _Float16* wth = inp ? wkh : wqh;
    const _Float16* wtl = inp ? wkl : wql;
    const float* bias = inp ? bk : bq;
    _Float16* ozh = inp ? kzh : qzh;
    _Float16* ozl = inp ? kzl : qzl;

    const int m0 = blockIdx.x * 64;
    const int hc = blockIdx.y >> 2;
    const int n0 = (blockIdx.y & 3) * 128;
    __shared__ char lds[32768];
    const int tid = threadIdx.x, wv = tid >> 6, ln = tid & 63;
    const int wr = wv >> 1, wc = wv & 1, lm32 = ln & 31;

    const size_t abase = ((size_t)((m0 >> 5) + wr)) * 32 * 512 + ln * 8;
    const _Float16* pxc[2] = { xch + abase, xcl + abase };
    const _Float16* pxs[2] = { xsh + abase, xsl + abase };

    const char* spB[4]; int dpB[4];
#pragma unroll
    for (int u = 0; u < 4; ++u) {
        const int g = wv * 4 + u;
        const int jt = g >> 2, hl = (g >> 1) & 1, ks = g & 1;
        const _Float16* base = (hl ? wtl : wth) + (size_t)hc * 262144;
        spB[u] = (const char*)(base
                 + ((size_t)(((n0 + jt * 32) >> 5) * 32 + ks)) * 512 + ln * 8);
        dpB[u] = g * 1024;
    }

    f32x16 ach[2] = {}, acl[2] = {}, ash[2] = {}, asl[2] = {};

    auto LOADA = [&](int s, half8 (&ac)[2][2], half8 (&as)[2][2]) {
#pragma unroll
        for (int hl = 0; hl < 2; ++hl)
#pragma unroll
            for (int ks = 0; ks < 2; ++ks) {
                ac[hl][ks] = *(const half8*)(pxc[hl] + (2 * s + ks) * 512);
                as[hl][ks] = *(const half8*)(pxs[hl] + (2 * s + ks) * 512);
            }
    };
    auto STAGEB = [&](int s, int buf) {
#pragma unroll
        for (int u = 0; u < 4; ++u)
            gll16(spB[u] + (size_t)s * 2048, lds + buf + dpB[u]);
    };
    auto MSTEP = [&](int buf, half8 (&ac)[2][2], half8 (&as)[2][2]) {
        half8 w0[2][2], w1[2][2];
#pragma unroll
        for (int ks = 0; ks < 2; ++ks)
#pragma unroll
            for (int j = 0; j < 2; ++j) {
                const int gb = (wc * 2 + j) * 4 + ks;
                w0[ks][j] = *(const half8*)(lds + buf + gb * 1024 + ln * 16);
                w1[ks][j] = *(const half8*)(lds + buf + (gb + 2) * 1024 + ln * 16);
            }
        __builtin_amdgcn_s_setprio(1);
#pragma unroll
        for (int ks = 0; ks < 2; ++ks)
#pragma unroll
            for (int j = 0; j < 2; ++j) {
                ach[j] = MFMA32(ac[0][ks], w0[ks][j], ach[j]);
                acl[j] = MFMA32(ac[0][ks], w1[ks][j], acl[j]);
                acl[j] = MFMA32(ac[1][ks], w0[ks][j], acl[j]);
                ash[j] = MFMA32(as[0][ks], w0[ks][j], ash[j]);
                asl[j] = MFMA32(as[0][ks], w1[ks][j], asl[j]);
                asl[j] = MFMA32(as[1][ks], w0[ks][j], asl[j]);
            }
        __builtin_amdgcn_s_setprio(0);
    };

    half8 Ac0[2][2], As0[2][2], Ac1[2][2], As1[2][2];
    LOADA(0, Ac0, As0); STAGEB(0, 0);
    const int NS = 16;
    for (int s = 0; s < NS; s += 2) {
        __syncthreads();
        STAGEB(s + 1, 16384); LOADA(s + 1, Ac1, As1);
        MSTEP(0, Ac0, As0);
        __syncthreads();
        if (s + 2 < NS) { STAGEB(s + 2, 0); LOADA(s + 2, Ac0, As0); }
        MSTEP(16384, Ac1, As1);
    }

    const float LS = 1.0f / 4096.0f;
    const int b = m0 >> 10, tbase = m0 & 1023;
    const size_t zz = (size_t)(b * hcnt + hc);
    const size_t zb = zz << 20;
    __syncthreads();
    // LDS-repack epilogue: 2 plane rounds (hi, lo), 32KB frag tile each.
#pragma unroll
    for (int p = 0; p < 2; ++p) {
        if (p) __syncthreads();
#pragma unroll
        for (int j = 0; j < 2; ++j) {
            const int nloc = wc * 64 + j * 32 + lm32;
            const float bval = bias[(size_t)(h0 + hc) * 512 + n0 + nloc];
            const int kk = 2 * nloc;
#pragma unroll
            for (int r = 0; r < 16; ++r) {
                const int mloc = wr * 32 + ROWOF(r, ln);
                float yc = ach[j][r] + acl[j][r] * LS + bval;
                float ys = ash[j][r] + asl[j][r] * LS;
                float inv = 1.0f / sqrtf(fmaxf(yc * yc + ys * ys, 1e-36f));
                _Float16 c_h, c_l, s_h, s_l;
                split2(yc * inv, c_h, c_l);
                split2(ys * inv, s_h, s_l);
                half2v pr;
                pr[0] = p ? c_l : c_h;
                pr[1] = p ? s_l : s_h;
                *(half2v*)(lds + ((mloc >> 5) * 16 + (kk >> 4)) * 1024
                    + (mloc & 31) * 16 + 512 * ((kk >> 3) & 1) + (kk & 7) * 2) = pr;
            }
        }
        __syncthreads();
        _Float16* op = p ? ozl : ozh;
#pragma unroll
        for (int w = 0; w < 8; ++w) {
            const int u = w * 256 + tid;
            const int f = u >> 6, within = u & 63;
            const int ms = f >> 4, kf = f & 15;
            *(half8*)(op + zb + (((size_t)(tbase >> 5) + ms) * 64 + (n0 >> 3) + kf) * 512
                      + within * 8) = *(const half8*)(lds + f * 1024 + within * 16);
        }
    }
}

// ---------------------------------------------------------------------------
// proj_v: same GEMM, epilogue -> vT planes (frag M=512 d, K=1024 t) via per-plane
// LDS transpose [128][80] + frag-ordered coalesced copy-out.
// ---------------------------------------------------------------------------
__global__ __launch_bounds__(256, 2) void proj_v(
    const _Float16* __restrict__ xch, const _Float16* __restrict__ xcl,
    const _Float16* __restrict__ xsh, const _Float16* __restrict__ xsl,
    const _Float16* __restrict__ wth, const _Float16* __restrict__ wtl,
    const float* __restrict__ bias,
    _Float16* __restrict__ vc_h, _Float16* __restrict__ vc_l,
    _Float16* __restrict__ vs_h, _Float16* __restrict__ vs_l,
    int h0, int hcnt)
{
    const int m0 = blockIdx.x * 64;
    const int hc = blockIdx.y >> 2;
    const int n0 = (blockIdx.y & 3) * 128;
    __shared__ char lds[32768];
    const int tid = threadIdx.x, wv = tid >> 6, ln = tid & 63;
    const int wr = wv >> 1, wc = wv & 1, lm32 = ln & 31;

    const size_t abase = ((size_t)((m0 >> 5) + wr)) * 32 * 512 + ln * 8;
    const _Float16* pxc[2] = { xch + abase, xcl + abase };
    const _Float16* pxs[2] = { xsh + abase, xsl + abase };

    const char* spB[4]; int dpB[4];
#pragma unroll
    for (int u = 0; u < 4; ++u) {
        const int g = wv * 4 + u;
        const int jt = g >> 2, hl = (g >> 1) & 1, ks = g & 1;
        const _Float16* base = (hl ? wtl : wth) + (size_t)hc * 262144;
        spB[u] = (const char*)(base
                 + ((size_t)(((n0 + jt * 32) >> 5) * 32 + ks)) * 512 + ln * 8);
        dpB[u] = g * 1024;
    }

    f32x16 ach[2] = {}, acl[2] = {}, ash[2] = {}, asl[2] = {};

    auto LOADA = [&](int s, half8 (&ac)[2][2], half8 (&as)[2][2]) {
#pragma unroll
        for (int hl = 0; hl < 2; ++hl)
#pragma unroll
            for (int ks = 0; ks < 2; ++ks) {
                ac[hl][ks] = *(const half8*)(pxc[hl] + (2 * s + ks) * 512);
                as[hl][ks] = *(const half8*)(pxs[hl] + (2 * s + ks) * 512);
            }
    };
    auto STAGEB = [&](int s, int buf) {
#pragma unroll
        for (int u = 0; u < 4; ++u)
            gll16(spB[u] + (size_t)s * 2048, lds + buf + dpB[u]);
    };
    auto MSTEP = [&](int buf, half8 (&ac)[2][2], half8 (&as)[2][2]) {
        half8 w0[2][2], w1[2][2];
#pragma unroll
        for (int ks = 0; ks < 2; ++ks)
#pragma unroll
            for (int j = 0; j < 2; ++j) {
                const int gb = (wc * 2 + j) * 4 + ks;
                w0[ks][j] = *(const half8*)(lds + buf + gb * 1024 + ln * 16);
                w1[ks][j] = *(const half8*)(lds + buf + (gb + 2) * 1024 + ln * 16);
            }
        __builtin_amdgcn_s_setprio(1);
#pragma unroll
        for (int ks = 0; ks < 2; ++ks)
#pragma unroll
            for (int j = 0; j < 2; ++j) {
                ach[j] = MFMA32(ac[0][ks], w0[ks][j], ach[j]);
                acl[j] = MFMA32(ac[0][ks], w1[ks][j], acl[j]);
                acl[j] = MFMA32(ac[1][ks], w0[ks][j], acl[j]);
                ash[j] = MFMA32(as[0][ks], w0[ks][j], ash[j]);
                asl[j] = MFMA32(as[0][ks], w1[ks][j], asl[j]);
                asl[j] = MFMA32(as[1][ks], w0[ks][j], asl[j]);
            }
        __builtin_amdgcn_s_setprio(0);
    };

    half8 Ac0[2][2], As0[2][2], Ac1[2][2], As1[2][2];
    LOADA(0, Ac0, As0); STAGEB(0, 0);
    const int NS = 16;
    for (int s = 0; s < NS; s += 2) {
        __syncthreads();
        STAGEB(s + 1, 16384); LOADA(s + 1, Ac1, As1);
        MSTEP(0, Ac0, As0);
        __syncthreads();
        if (s + 2 < NS) { STAGEB(s + 2, 0); LOADA(s + 2, Ac0, As0); }
        MSTEP(16384, Ac1, As1);
    }

    const float LS = 1.0f / 4096.0f;
    const int b = m0 >> 10, tbase = m0 & 1023;
    const size_t zz = (size_t)(b * hcnt + hc);
    const size_t zvb = zz * 524288;
    _Float16* T = (_Float16*)lds;
#pragma unroll
    for (int p = 0; p < 4; ++p) {
        __syncthreads();
#pragma unroll
        for (int j = 0; j < 2; ++j) {
            const int dloc = wc * 64 + j * 32 + lm32;
            const float bval = bias[(size_t)(h0 + hc) * 512 + n0 + dloc];
#pragma unroll
            for (int r = 0; r < 16; ++r) {
                const int tloc = wr * 32 + ROWOF(r, ln);
                float yc = ach[j][r] + acl[j][r] * LS + bval;
                float ys = ash[j][r] + asl[j][r] * LS;
                float inv = 1.0f / sqrtf(fmaxf(yc * yc + ys * ys, 1e-36f));
                _Float16 hh, ll;
                if (p < 2) split2(yc * inv, hh, ll);
                else       split2(ys * inv, hh, ll);
                T[dloc * 80 + tloc] = (p & 1) ? ll : hh;
            }
        }
        __syncthreads();
        _Float16* op = (p == 0) ? vc_h : (p == 1) ? vc_l : (p == 2) ? vs_h : vs_l;
#pragma unroll
        for (int w = 0; w < 4; ++w) {
            const int u = w * 256 + tid;
            const int f = u >> 6, within = u & 63;
            const int ds_ = f >> 2, tf = f & 3;
            const int d = ds_ * 32 + (within & 31);
            const int tl = tf * 16 + (within >> 5) * 8;
            half8 vv = *(const half8*)(T + d * 80 + tl);
            *(half8*)(op + zvb + (((size_t)((n0 >> 5) + ds_)) * 64 + (tbase >> 4) + tf) * 512
                      + within * 8) = vv;
        }
    }
}

// ---------------------------------------------------------------------------
// scores: S[z][t][T] = (qz . kz)/512, K=1024 (frag layout). Unchanged from r6.
// ---------------------------------------------------------------------------
__global__ __launch_bounds__(256, 2) void scores_mfma(
    const _Float16* __restrict__ qzh, const _Float16* __restrict__ qzl,
    const _Float16* __restrict__ kzh, const _Float16* __restrict__ kzl,
    float* __restrict__ S, int Z)
{
    const int wg = xcdswz(blockIdx.x, Z * 64);
    const int z = wg >> 6;
    const int rem = wg & 63;
    const int m0 = (rem & 7) << 7, n0 = (rem >> 3) << 7;
    __shared__ char lds[32768];
    const size_t zb = (size_t)z << 20;
    const int tid = threadIdx.x, wv = tid >> 6, ln = tid & 63;
    const int wr = wv >> 1, wc = wv & 1, lm32 = ln & 31;

    const _Float16* pa[2] = { qzh + zb + ln * 8, qzl + zb + ln * 8 };
    const char* spB[4]; int dpB[4];
#pragma unroll
    for (int u = 0; u < 4; ++u) {
        const int g = wv * 4 + u;
        const int jt = g >> 2, hl = (g >> 1) & 1, ks = g & 1;
        spB[u] = (const char*)((hl ? kzl : kzh) + zb
                 + ((size_t)(((n0 + jt * 32) >> 5) * 64 + ks)) * 512 + ln * 8);
        dpB[u] = g * 1024;
    }

    f32x16 acch[2][2] = {}, accl[2][2] = {};

    auto LOADA = [&](int s, half8 (&a)[2][2][2]) {
#pragma unroll
        for (int hl = 0; hl < 2; ++hl)
#pragma unroll
            for (int i = 0; i < 2; ++i)
#pragma unroll
                for (int ks = 0; ks < 2; ++ks)
                    a[hl][i][ks] = *(const half8*)(pa[hl]
                        + ((size_t)((m0 >> 5) + wr * 2 + i) * 64 + 2 * s + ks) * 512);
    };
    auto STAGEB = [&](int s, int buf) {
#pragma unroll
        for (int u = 0; u < 4; ++u)
            gll16(spB[u] + (size_t)s * 2048, lds + buf + dpB[u]);
    };
    auto MSTEP = [&](int buf, half8 (&a)[2][2][2]) {
        half8 bh[2][2], bl[2][2];
#pragma unroll
        for (int ks = 0; ks < 2; ++ks)
#pragma unroll
            for (int j = 0; j < 2; ++j) {
                const int gb = (wc * 2 + j) * 4 + ks;
                bh[ks][j] = *(const half8*)(lds + buf + gb * 1024 + ln * 16);
                bl[ks][j] = *(const half8*)(lds + buf + (gb + 2) * 1024 + ln * 16);
            }
        __builtin_amdgcn_s_setprio(1);
#pragma unroll
        for (int ks = 0; ks < 2; ++ks)
#pragma unroll
            for (int i = 0; i < 2; ++i)
#pragma unroll
                for (int j = 0; j < 2; ++j) {
                    acch[i][j] = MFMA32(a[0][i][ks], bh[ks][j], acch[i][j]);
                    accl[i][j] = MFMA32(a[0][i][ks], bl[ks][j], accl[i][j]);
                    accl[i][j] = MFMA32(a[1][i][ks], bh[ks][j], accl[i][j]);
                }
        __builtin_amdgcn_s_setprio(0);
    };

    half8 A0[2][2][2], A1[2][2][2];
    LOADA(0, A0); STAGEB(0, 0);
    const int NS = 32;
    for (int s = 0; s < NS; s += 2) {
        __syncthreads();
        STAGEB(s + 1, 16384); LOADA(s + 1, A1);
        MSTEP(0, A0);
        __syncthreads();
        if (s + 2 < NS) { STAGEB(s + 2, 0); LOADA(s + 2, A0); }
        MSTEP(16384, A1);
    }
    const float LS = 1.0f / 4096.0f, SC = 1.0f / 512.0f;
#pragma unroll
    for (int i = 0; i < 2; ++i)
#pragma unroll
        for (int j = 0; j < 2; ++j)
#pragma unroll
            for (int r = 0; r < 16; ++r) {
                const int row = m0 + wr * 64 + i * 32 + ROWOF(r, ln);
                const int col = n0 + wc * 64 + j * 32 + lm32;
                S[zb + (size_t)row * 1024 + col] =
                    (acch[i][j][r] + accl[i][j][r] * LS) * SC;
            }
}

// ---------------------------------------------------------------------------
// softmax_frag: 32 rows per block, no max-sub (|S|<=2 always), 2-pass,
// LDS frag repack, fully coalesced 16B P writes (pv-A frag layout).
// ---------------------------------------------------------------------------
__global__ __launch_bounds__(256) void softmax_frag(
    const float* __restrict__ S, _Float16* __restrict__ Ph, _Float16* __restrict__ Pl)
{
    const int z = blockIdx.x >> 5, tt = blockIdx.x & 31;
    const float* Sb = S + ((size_t)z << 20) + ((size_t)tt << 15);
    const int tid = threadIdx.x;
    const int row = tid >> 3, lc = tid & 7;
    __shared__ float rsum[32];
    __shared__ char fb[32768];
    const float* prow = Sb + (size_t)row * 1024 + lc * 128;
    float s = 0.f;
    for (int q = 0; q < 32; ++q) {
        float4 v = *(const float4*)(prow + q * 4);
        s += (expf(v.x) + expf(v.y)) + (expf(v.z) + expf(v.w));
    }
    s += __shfl_xor(s, 1); s += __shfl_xor(s, 2); s += __shfl_xor(s, 4);
    if (lc == 0) rsum[row] = s;
    __syncthreads();
    const float inv = 1.0f / rsum[row];
    for (int c = 0; c < 4; ++c) {
        if (c) __syncthreads();
        const float* pc = Sb + (size_t)row * 1024 + c * 256 + lc * 32;
#pragma unroll
        for (int q = 0; q < 8; ++q) {
            float4 v = *(const float4*)(pc + q * 4);
            half4 hv, lv; _Float16 a, b;
            split2(expf(v.x) * inv, a, b); hv[0] = a; lv[0] = b;
            split2(expf(v.y) * inv, a, b); hv[1] = a; lv[1] = b;
            split2(expf(v.z) * inv, a, b); hv[2] = a; lv[2] = b;
            split2(expf(v.w) * inv, a, b); hv[3] = a; lv[3] = b;
            const int f = lc * 2 + (q >> 2);
            const int boff = f * 1024 + row * 16 + 512 * ((q >> 1) & 1) + (q & 1) * 8;
            *(half4*)(fb + boff) = hv;
            *(half4*)(fb + 16384 + boff) = lv;
        }
        __syncthreads();
#pragma unroll
        for (int w = 0; w < 8; ++w) {
            const int u = w * 256 + tid;
            const int pl = u >> 10, rest = u & 1023;
            const int f = rest >> 6, within = rest & 63;
            _Float16* dst = (pl ? Pl : Ph) + ((size_t)z << 20)
                          + ((size_t)(tt * 64 + c * 16 + f)) * 512 + within * 8;
            *(half8*)dst = *(const half8*)(fb + pl * 16384 + f * 1024 + within * 16);
        }
    }
}

// ---------------------------------------------------------------------------
// pv: out = P @ vz, normalize, split -> rcs planes (frag M=2048, K=4096).
// Main loop unchanged; epilogue LDS-repacked (4 plane rounds).
// ---------------------------------------------------------------------------
__global__ __launch_bounds__(256, 2) void pv_mfma(
    const _Float16* __restrict__ Ph, const _Float16* __restrict__ Pl,
    const _Float16* __restrict__ vch, const _Float16* __restrict__ vcl,
    const _Float16* __restrict__ vsh, const _Float16* __restrict__ vsl,
    _Float16* __restrict__ rch, _Float16* __restrict__ rcl,
    _Float16* __restrict__ rsh, _Float16* __restrict__ rsl,
    int h0, int hcnt, int Z)
{
    const int wg = xcdswz(blockIdx.x, Z * 64);
    const int z = wg >> 6;
    const int rem = wg & 63;
    const int m0 = (rem & 7) << 7, n0 = (rem >> 3) << 6;
    __shared__ char lds[32768];
    const int tid = threadIdx.x, wv = tid >> 6, ln = tid & 63;
    const int wr = wv >> 1, wc = wv & 1, lm32 = ln & 31;

    const size_t zb = (size_t)z << 20, zvb = (size_t)z * 524288;
    const _Float16* pa[2] = { Ph + zb + ln * 8, Pl + zb + ln * 8 };
    const char* spB[4]; int dpB[4];
#pragma unroll
    for (int u = 0; u < 4; ++u) {
        const int g = wv * 4 + u;
        const int pl = g >> 3, dt = (g >> 2) & 1, hl = (g >> 1) & 1, ks = g & 1;
        const _Float16* base = pl ? (hl ? vsl : vsh) : (hl ? vcl : vch);
        spB[u] = (const char*)(base + zvb
                 + ((size_t)(((n0 + dt * 32) >> 5) * 64 + ks)) * 512 + ln * 8);
        dpB[u] = g * 1024;
    }

    f32x16 ac_h[2] = {}, ac_l[2] = {}, as_h[2] = {}, as_l[2] = {};

    auto LOADA = [&](int s, half8 (&a)[2][2][2]) {
#pragma unroll
        for (int hl = 0; hl < 2; ++hl)
#pragma unroll
            for (int i = 0; i < 2; ++i)
#pragma unroll
                for (int ks = 0; ks < 2; ++ks)
                    a[hl][i][ks] = *(const half8*)(pa[hl]
                        + ((size_t)((m0 >> 5) + wr * 2 + i) * 64 + 2 * s + ks) * 512);
    };
    auto STAGEB = [&](int s, int buf) {
#pragma unroll
        for (int u = 0; u < 4; ++u)
            gll16(spB[u] + (size_t)s * 2048, lds + buf + dpB[u]);
    };
    auto MSTEP = [&](int buf, half8 (&a)[2][2][2]) {
        half8 vc[2][2], vs[2][2];
#pragma unroll
        for (int hl = 0; hl < 2; ++hl)
#pragma unroll
            for (int ks = 0; ks < 2; ++ks) {
                vc[hl][ks] = *(const half8*)(lds + buf + (wc * 4 + hl * 2 + ks) * 1024 + ln * 16);
                vs[hl][ks] = *(const half8*)(lds + buf + (8 + wc * 4 + hl * 2 + ks) * 1024 + ln * 16);
            }
        __builtin_amdgcn_s_setprio(1);
#pragma unroll
        for (int ks = 0; ks < 2; ++ks)
#pragma unroll
            for (int i = 0; i < 2; ++i) {
                ac_h[i] = MFMA32(a[0][i][ks], vc[0][ks], ac_h[i]);
                ac_l[i] = MFMA32(a[0][i][ks], vc[1][ks], ac_l[i]);
                ac_l[i] = MFMA32(a[1][i][ks], vc[0][ks], ac_l[i]);
                as_h[i] = MFMA32(a[0][i][ks], vs[0][ks], as_h[i]);
                as_l[i] = MFMA32(a[0][i][ks], vs[1][ks], as_l[i]);
                as_l[i] = MFMA32(a[1][i][ks], vs[0][ks], as_l[i]);
            }
        __builtin_amdgcn_s_setprio(0);
    };

    half8 A0[2][2][2], A1[2][2][2];
    LOADA(0, A0); STAGEB(0, 0);
    const int NS = 32;
    for (int s = 0; s < NS; s += 2) {
        __syncthreads();
        STAGEB(s + 1, 16384); LOADA(s + 1, A1);
        MSTEP(0, A0);
        __syncthreads();
        if (s + 2 < NS) { STAGEB(s + 2, 0); LOADA(s + 2, A0); }
        MSTEP(16384, A1);
    }
    const float LS = 1.0f / 4096.0f;
    const int b = z / hcnt, hg = h0 + z % hcnt;
    const size_t mrow = (size_t)((b * 1024 + m0) >> 5);
    const size_t kcol = (size_t)(hg * 512 + n0) >> 4;
    __syncthreads();
#pragma unroll
    for (int p = 0; p < 4; ++p) {
        if (p) __syncthreads();
#pragma unroll
        for (int i = 0; i < 2; ++i)
#pragma unroll
            for (int r = 0; r < 16; ++r) {
                const int mloc = wr * 64 + i * 32 + ROWOF(r, ln);
                const int kloc = wc * 32 + lm32;
                float zc = ac_h[i][r] + ac_l[i][r] * LS;
                float zs = as_h[i][r] + as_l[i][r] * LS;
                float inv = 1.0f / sqrtf(fmaxf(zc * zc + zs * zs, 1e-36f));
                _Float16 hh, ll;
                if (p < 2) split2(zc * inv, hh, ll);
                else       split2(zs * inv, hh, ll);
                *(_Float16*)(lds + ((mloc >> 5) * 4 + (kloc >> 4)) * 1024
                    + (mloc & 31) * 16 + 512 * ((kloc >> 3) & 1) + (kloc & 7) * 2)
                    = (p & 1) ? ll : hh;
            }
        __syncthreads();
        _Float16* op = (p == 0) ? rch : (p == 1) ? rcl : (p == 2) ? rsh : rsl;
#pragma unroll
        for (int w = 0; w < 4; ++w) {
            const int u = w * 256 + tid;
            const int f = u >> 6, within = u & 63;
            const int ms = f >> 2, kf = f & 3;
            *(half8*)(op + ((mrow + ms) * 256 + kcol + kf) * 512 + within * 8)
                = *(const half8*)(lds + f * 1024 + within * 16);
        }
    }
}

// ---------------------------------------------------------------------------
// final (K-split): partial z = rz @ wo. Unchanged from r6 (coalesced f32 writes).
// ---------------------------------------------------------------------------
__global__ __launch_bounds__(256, 2) void final_mfma(
    const _Float16* __restrict__ rch, const _Float16* __restrict__ rcl,
    const _Float16* __restrict__ rsh, const _Float16* __restrict__ rsl,
    const _Float16* __restrict__ woh, const _Float16* __restrict__ wol,
    float* __restrict__ pbuf)
{
    const int m0 = blockIdx.x * 64, n0 = blockIdx.y * 128;
    const int kspl = blockIdx.z;
    const int kf = kspl * 64;
    __shared__ char lds[32768];
    const int tid = threadIdx.x, wv = tid >> 6, ln = tid & 63;
    const int wr = wv >> 1, wc = wv & 1, lm32 = ln & 31;

    const size_t abase = ((size_t)((m0 >> 5) + wr) * 256 + kf) * 512 + ln * 8;
    const _Float16* prc[2] = { rch + abase, rcl + abase };
    const _Float16* prs[2] = { rsh + abase, rsl + abase };
    const char* spB[4]; int dpB[4];
#pragma unroll
    for (int u = 0; u < 4; ++u) {
        const int g = wv * 4 + u;
        const int jt = g >> 2, hl = (g >> 1) & 1, ks = g & 1;
        spB[u] = (const char*)((hl ? wol : woh)
                 + ((size_t)(((n0 + jt * 32) >> 5) * 256 + kf + ks)) * 512 + ln * 8);
        dpB[u] = g * 1024;
    }

    f32x16 rr_h[2] = {}, rr_l[2] = {}, ri_h[2] = {}, ri_l[2] = {};

    auto LOADA = [&](int s, half8 (&ac)[2][2], half8 (&as)[2][2]) {
#pragma unroll
        for (int hl = 0; hl < 2; ++hl)
#pragma unroll
            for (int ks = 0; ks < 2; ++ks) {
                ac[hl][ks] = *(const half8*)(prc[hl] + (2 * s + ks) * 512);
                as[hl][ks] = *(const half8*)(prs[hl] + (2 * s + ks) * 512);
            }
    };
    auto STAGEB = [&](int s, int buf) {
#pragma unroll
        for (int u = 0; u < 4; ++u)
            gll16(spB[u] + (size_t)s * 2048, lds + buf + dpB[u]);
    };
    auto MSTEP = [&](int buf, half8 (&ac)[2][2], half8 (&as)[2][2]) {
        half8 w0[2][2], w1[2][2];
#pragma unroll
        for (int ks = 0; ks < 2; ++ks)
#pragma unroll
            for (int j = 0; j < 2; ++j) {
                const int gb = (wc * 2 + j) * 4 + ks;
                w0[ks][j] = *(const half8*)(lds + buf + gb * 1024 + ln * 16);
                w1[ks][j] = *(const half8*)(lds + buf + (gb + 2) * 1024 + ln * 16);
            }
        __builtin_amdgcn_s_setprio(1);
#pragma unroll
        for (int ks = 0; ks < 2; ++ks)
#pragma unroll
            for (int j = 0; j < 2; ++j) {
                rr_h[j] = MFMA32(ac[0][ks], w0[ks][j], rr_h[j]);
                rr_l[j] = MFMA32(ac[0][ks], w1[ks][j], rr_l[j]);
                rr_l[j] = MFMA32(ac[1][ks], w0[ks][j], rr_l[j]);
                ri_h[j] = MFMA32(as[0][ks], w0[ks][j], ri_h[j]);
                ri_l[j] = MFMA32(as[0][ks], w1[ks][j], ri_l[j]);
                ri_l[j] = MFMA32(as[1][ks], w0[ks][j], ri_l[j]);
            }
        __builtin_amdgcn_s_setprio(0);
    };

    half8 Ac0[2][2], As0[2][2], Ac1[2][2], As1[2][2];
    LOADA(0, Ac0, As0); STAGEB(0, 0);
    const int NS = 32;
    for (int s = 0; s < NS; s += 2) {
        __syncthreads();
        STAGEB(s + 1, 16384); LOADA(s + 1, Ac1, As1);
        MSTEP(0, Ac0, As0);
        __syncthreads();
        if (s + 2 < NS) { STAGEB(s + 2, 0); LOADA(s + 2, Ac0, As0); }
        MSTEP(16384, Ac1, As1);
    }
    const float LS = 1.0f / 4096.0f;
#pragma unroll
    for (int j = 0; j < 2; ++j) {
        const int ng = n0 + wc * 64 + j * 32 + lm32;
#pragma unroll
        for (int r = 0; r < 16; ++r) {
            const int mg = m0 + wr * 32 + ROWOF(r, ln);
            float2 v;
            v.x = rr_h[j][r] + rr_l[j][r] * LS;
            v.y = ri_h[j][r] + ri_l[j][r] * LS;
            *(float2*)&pbuf[((size_t)(kspl * 2048 + mg) * 512 + ng) * 2] = v;
        }
    }
}

// ---------------------------------------------------------------------------
// combine: out[m][n] = atan2(sum zi, sum zr + bo[n]) / pi
// ---------------------------------------------------------------------------
__global__ __launch_bounds__(256) void final_combine(
    const float* __restrict__ pbuf, const float* __restrict__ bo,
    float* __restrict__ out, int KS)
{
    const int m = blockIdx.x, t = threadIdx.x;
    float4 acc = {0.f, 0.f, 0.f, 0.f};
    for (int s = 0; s < KS; ++s) {
        float4 v = *(const float4*)&pbuf[(size_t)(s * 2048 + m) * 1024 + t * 4];
        acc.x += v.x; acc.y += v.y; acc.z += v.z; acc.w += v.w;
    }
    const int n0 = t * 2;
    out[(size_t)m * 512 + n0]     = atan2f(acc.y, acc.x + bo[n0]) / PI_F;
    out[(size_t)m * 512 + n0 + 1] = atan2f(acc.w, acc.z + bo[n0 + 1]) / PI_F;
}

// ---------------------------------------------------------------------------
extern "C" void kernel_launch(void* const* d_in, const int* in_sizes, int n_in,
                              void* d_out, int out_size, void* d_ws, size_t ws_size,
                              hipStream_t stream)
{
    (void)in_sizes; (void)n_in; (void)out_size;
    const float* query    = (const float*)d_in[0];
    const float* keyvalue = (const float*)d_in[1];
    const float* wq = (const float*)d_in[2];
    const float* bq = (const float*)d_in[3];
    const float* wk = (const float*)d_in[4];
    const float* bk = (const float*)d_in[5];
    const float* wv = (const float*)d_in[6];
    const float* bv = (const float*)d_in[7];
    const float* wo = (const float*)d_in[8];
    const float* bo = (const float*)d_in[9];
    float* out = (float*)d_out;

    int hcnt;
    if (ws_size >= (size_t)320 * 1024 * 1024) hcnt = 8;
    else if (ws_size >= (size_t)240 * 1024 * 1024) hcnt = 4;
    else hcnt = 2;
    const int Z = 2 * hcnt;
    const int KS = (hcnt == 2) ? 2 : 4;

    char* p = (char*)d_ws;
    auto alloc = [&](size_t bytes) {
        char* r = p;
        p += (bytes + 255) & ~(size_t)255;
        return r;
    };
    const size_t PLX = (size_t)2048 * 512;
    _Float16* xq[4]; for (int i = 0; i < 4; ++i) xq[i] = (_Float16*)alloc(PLX * 2);
    _Float16* xk[4]; for (int i = 0; i < 4; ++i) xk[i] = (_Float16*)alloc(PLX * 2);
    _Float16* woT[2]; for (int i = 0; i < 2; ++i) woT[i] = (_Float16*)alloc((size_t)512 * 4096 * 2);
    const size_t WTE = (size_t)hcnt * 512 * 512;
    _Float16* wqT[2]; for (int i = 0; i < 2; ++i) wqT[i] = (_Float16*)alloc(WTE * 2);
    _Float16* wkT[2]; for (int i = 0; i < 2; ++i) wkT[i] = (_Float16*)alloc(WTE * 2);
    _Float16* wvT[2]; for (int i = 0; i < 2; ++i) wvT[i] = (_Float16*)alloc(WTE * 2);
    const size_t QZE = (size_t)Z * 1024 * 1024;
    _Float16* qz[2]; for (int i = 0; i < 2; ++i) qz[i] = (_Float16*)alloc(QZE * 2);
    _Float16* kz[2]; for (int i = 0; i < 2; ++i) kz[i] = (_Float16*)alloc(QZE * 2);
    float* S = (float*)alloc(QZE * 4);
    const size_t VTE = (size_t)Z * 512 * 1024;
    _Float16* vT[4]; for (int i = 0; i < 4; ++i) vT[i] = (_Float16*)alloc(VTE * 2);
    const size_t RCE = (size_t)2048 * 4096;
    _Float16* rcs[4];
    if (hcnt == 8) {
        for (int i = 0; i < 4; ++i) rcs[i] = (_Float16*)((char*)qz[0] + (size_t)i * RCE * 2);
    } else {
        for (int i = 0; i < 4; ++i) rcs[i] = (_Float16*)alloc(RCE * 2);
    }
    _Float16* Ph = kz[0];
    _Float16* Pl = kz[1];
    float* pbuf = (float*)kz[0];

    dim3 blk(256);

    encode_phasor<<<dim3(64, 2, 2), blk, 0, stream>>>(
        query, keyvalue,
        xq[0], xq[1], xq[2], xq[3], xk[0], xk[1], xk[2], xk[3]);
    tsplit64<<<dim3(64, 8, 1), blk, 0, stream>>>(wo, woT[0], woT[1], 4096, 512);

    for (int c = 0; c < 8 / hcnt; ++c) {
        const int h0 = c * hcnt;
        tsplit_qkv<<<dim3(8, 8, 3 * hcnt), blk, 0, stream>>>(
            wq + (size_t)h0 * 262144, wk + (size_t)h0 * 262144, wv + (size_t)h0 * 262144,
            wqT[0], wqT[1], wkT[0], wkT[1], wvT[0], wvT[1], hcnt);

        proj_qk<<<dim3(32, hcnt * 4, 2), blk, 0, stream>>>(
            xq[0], xq[1], xq[2], xq[3], xk[0], xk[1], xk[2], xk[3],
            wqT[0], wqT[1], wkT[0], wkT[1], bq, bk,
            qz[0], qz[1], kz[0], kz[1], h0, hcnt);
        proj_v<<<dim3(32, hcnt * 4), blk, 0, stream>>>(
            xk[0], xk[1], xk[2], xk[3], wvT[0], wvT[1], bv,
            vT[0], vT[1], vT[2], vT[3], h0, hcnt);

        scores_mfma<<<dim3(Z * 64), blk, 0, stream>>>(qz[0], qz[1], kz[0], kz[1], S, Z);
        softmax_frag<<<dim3(Z * 32), blk, 0, stream>>>(S, Ph, Pl);
        pv_mfma<<<dim3(Z * 64), blk, 0, stream>>>(
            Ph, Pl, vT[0], vT[1], vT[2], vT[3],
            rcs[0], rcs[1], rcs[2], rcs[3], h0, hcnt, Z);
    }

    final_mfma<<<dim3(32, 4, KS), blk, 0, stream>>>(
        rcs[0], rcs[1], rcs[2], rcs[3], woT[0], woT[1], pbuf);
    final_combine<<<dim3(2048), blk, 0, stream>>>(pbuf, bo, out, KS);
}

// Round 9
// 548.249 us; speedup vs baseline: 1.1302x; 1.0709x over previous
//
#include <hip/hip_runtime.h>
#include <math.h>

// Phasor attention via split-fp16 MFMA (fp16x2 error-free splitting, ~fp32 accuracy).
// B=2, T=1024, D=512, H=8.
// Round 9 = Round 7 (known-good) + ONE change: softmax removed via positive-scale
// invariance (pv's z/|z| cancels the denominator exactly). P = exp(S/512) is
// computed in the scores epilogue and written split-fp16 directly in pv's A-frag
// layout (LDS frag-tile repack, coalesced 16B stores). softmax kernel deleted;
// the 64MB f32 S tensor never touches memory.

#define PI_F 3.14159274101257324f

typedef __attribute__((ext_vector_type(8))) _Float16 half8;
typedef __attribute__((ext_vector_type(4))) _Float16 half4;
typedef __attribute__((ext_vector_type(2))) _Float16 half2v;
typedef __attribute__((ext_vector_type(16))) float f32x16;
typedef unsigned int u32;

#define MFMA32(a, b, c) __builtin_amdgcn_mfma_f32_32x32x16_f16((a), (b), (c), 0, 0, 0)
// C/D layout for 32x32: col = lane&31, row = (reg&3) + 8*(reg>>2) + 4*(lane>>5)
#define ROWOF(r, ln) (((r) & 3) + 8 * ((r) >> 2) + 4 * ((ln) >> 5))

__device__ __forceinline__ void gll16(const void* g, void* l) {
    __builtin_amdgcn_global_load_lds(
        (const __attribute__((address_space(1))) u32*)g,
        (__attribute__((address_space(3))) u32*)l, 16, 0, 0);
}

__device__ __forceinline__ void split2(float x, _Float16& h, _Float16& l) {
    _Float16 hh = (_Float16)x;
    h = hh;
    l = (_Float16)((x - (float)hh) * 4096.0f);
}

// bijective XCD swizzle (nwg divisible by 8)
__device__ __forceinline__ int xcdswz(int bid, int nwg) {
    const int cpx = nwg >> 3;
    return (bid & 7) * cpx + (bid >> 3);
}

// ---------------------------------------------------------------------------
// encode: x [2048][512] f32 -> 4 phasor planes, frag layout (K=512, Kd16=32).
// ---------------------------------------------------------------------------
__global__ __launch_bounds__(256) void encode_phasor(
    const float* __restrict__ xq, const float* __restrict__ xkv,
    _Float16* __restrict__ qch, _Float16* __restrict__ qcl,
    _Float16* __restrict__ qsh, _Float16* __restrict__ qsl,
    _Float16* __restrict__ kch, _Float16* __restrict__ kcl,
    _Float16* __restrict__ ksh, _Float16* __restrict__ ksl)
{
    const int mt = blockIdx.x, yh = blockIdx.y, zi = blockIdx.z;
    const float* x = zi ? xkv : xq;
    __shared__ char fb[32768];
    const int tid = threadIdx.x;
    const int row = tid >> 3, lc = tid & 7;
    const float* xr = x + (size_t)(mt * 32 + row) * 512 + yh * 256;
    for (int c = 0; c < 2; ++c) {
        if (c) __syncthreads();
        half8 hs[4][2];
#pragma unroll
        for (int g = 0; g < 2; ++g)
#pragma unroll
            for (int q = 0; q < 2; ++q) {
                float4 v = *(const float4*)(xr + c * 128 + lc * 16 + g * 8 + q * 4);
                float cc[4], ss[4];
                sincosf(PI_F * v.x, &ss[0], &cc[0]);
                sincosf(PI_F * v.y, &ss[1], &cc[1]);
                sincosf(PI_F * v.z, &ss[2], &cc[2]);
                sincosf(PI_F * v.w, &ss[3], &cc[3]);
#pragma unroll
                for (int e = 0; e < 4; ++e) {
                    _Float16 a, b;
                    split2(cc[e], a, b); hs[0][g][q * 4 + e] = a; hs[1][g][q * 4 + e] = b;
                    split2(ss[e], a, b); hs[2][g][q * 4 + e] = a; hs[3][g][q * 4 + e] = b;
                }
            }
#pragma unroll
        for (int p = 0; p < 4; ++p) {
            char* base = fb + p * 8192 + lc * 1024 + row * 16;
            *(half8*)(base) = hs[p][0];
            *(half8*)(base + 512) = hs[p][1];
        }
        __syncthreads();
#pragma unroll
        for (int w = 0; w < 8; ++w) {
            const int u = w * 256 + tid;
            const int p = u >> 9, rest = u & 511;
            const int f = rest >> 6, within = rest & 63;
            _Float16* op;
            if (zi) op = (p == 0) ? kch : (p == 1) ? kcl : (p == 2) ? ksh : ksl;
            else    op = (p == 0) ? qch : (p == 1) ? qcl : (p == 2) ? qsh : qsl;
            const size_t fragG = (size_t)mt * 32 + yh * 16 + c * 8 + f;
            *(half8*)(op + fragG * 512 + within * 8) =
                *(const half8*)(fb + p * 8192 + f * 1024 + within * 16);
        }
    }
}

// ---------------------------------------------------------------------------
// tsplit64: w [h][K][N=512] f32 -> transposed split planes [h][512][K], frag.
// ---------------------------------------------------------------------------
__global__ __launch_bounds__(256) void tsplit64(
    const float* __restrict__ w, _Float16* __restrict__ th, _Float16* __restrict__ tl,
    int K, int N)
{
    const int kt = blockIdx.x, ntile = blockIdx.y, h = blockIdx.z;
    const int k0 = kt * 64, n0 = ntile * 64;
    __shared__ float T[64][65];
    const int tid = threadIdx.x;
    const float* wb = w + (size_t)h * K * N;
    {
        const int r = tid >> 4, c4 = (tid & 15) * 4;
#pragma unroll
        for (int rr = 0; rr < 64; rr += 16) {
            float4 v = *(const float4*)&wb[(size_t)(k0 + rr + r) * N + n0 + c4];
            T[rr + r][c4 + 0] = v.x; T[rr + r][c4 + 1] = v.y;
            T[rr + r][c4 + 2] = v.z; T[rr + r][c4 + 3] = v.w;
        }
    }
    __syncthreads();
    {
        const int n = n0 + (tid >> 2), kq = k0 + (tid & 3) * 16;
        half8 hv[2], lv[2];
#pragma unroll
        for (int q = 0; q < 16; ++q) {
            float f = T[kq - k0 + q][n - n0];
            _Float16 hh, ll; split2(f, hh, ll);
            hv[q >> 3][q & 7] = hh; lv[q >> 3][q & 7] = ll;
        }
        const size_t hb = (size_t)h * 512 * K;
        const size_t offA = hb + ((size_t)((n >> 5) * (K >> 4) + (kq >> 4))) * 512
                            + (n & 31) * 8;
        *(half8*)(th + offA) = hv[0]; *(half8*)(th + offA + 256) = hv[1];
        *(half8*)(tl + offA) = lv[0]; *(half8*)(tl + offA + 256) = lv[1];
    }
}

// tsplit_qkv: 3 weight tensors in one launch. Grid (8,8,3*hcnt).
__global__ __launch_bounds__(256) void tsplit_qkv(
    const float* __restrict__ wq, const float* __restrict__ wk,
    const float* __restrict__ wv,
    _Float16* __restrict__ qh, _Float16* __restrict__ ql,
    _Float16* __restrict__ kh, _Float16* __restrict__ kl,
    _Float16* __restrict__ vh, _Float16* __restrict__ vl, int hcnt)
{
    const int tsel = blockIdx.z / hcnt, h = blockIdx.z % hcnt;
    const int kt = blockIdx.x, ntile = blockIdx.y;
    const int k0 = kt * 64, n0 = ntile * 64;
    const float* w = (tsel == 0) ? wq : (tsel == 1) ? wk : wv;
    _Float16* th = (tsel == 0) ? qh : (tsel == 1) ? kh : vh;
    _Float16* tl = (tsel == 0) ? ql : (tsel == 1) ? kl : vl;
    __shared__ float T[64][65];
    const int tid = threadIdx.x;
    const float* wb = w + (size_t)h * 262144;
    {
        const int r = tid >> 4, c4 = (tid & 15) * 4;
#pragma unroll
        for (int rr = 0; rr < 64; rr += 16) {
            float4 v = *(const float4*)&wb[(size_t)(k0 + rr + r) * 512 + n0 + c4];
            T[rr + r][c4 + 0] = v.x; T[rr + r][c4 + 1] = v.y;
            T[rr + r][c4 + 2] = v.z; T[rr + r][c4 + 3] = v.w;
        }
    }
    __syncthreads();
    {
        const int n = n0 + (tid >> 2), kq = k0 + (tid & 3) * 16;
        half8 hv[2], lv[2];
#pragma unroll
        for (int q = 0; q < 16; ++q) {
            float f = T[kq - k0 + q][n - n0];
            _Float16 hh, ll; split2(f, hh, ll);
            hv[q >> 3][q & 7] = hh; lv[q >> 3][q & 7] = ll;
        }
        const size_t hb = (size_t)h * 262144;
        const size_t offA = hb + ((size_t)((n >> 5) * 32 + (kq >> 4))) * 512 + (n & 31) * 8;
        *(half8*)(th + offA) = hv[0]; *(half8*)(th + offA + 256) = hv[1];
        *(half8*)(tl + offA) = lv[0]; *(half8*)(tl + offA + 256) = lv[1];
    }
}

// ---------------------------------------------------------------------------
// proj_qk: y = phasor(x) @ w + bias -> normalize -> qz/kz (c,s interleaved,
// frag M=1024 K=1024). Block 64x128, waves 2x2, wave-tile 32x64, BK=32, NS=16.
// A direct global->reg; B LDS dbuf 2x16KB. z: 0=query, 1=key. LDS-repack epilogue.
// ---------------------------------------------------------------------------
__global__ __launch_bounds__(256, 2) void proj_qk(
    const _Float16* __restrict__ qch, const _Float16* __restrict__ qcl,
    const _Float16* __restrict__ qsh, const _Float16* __restrict__ qsl,
    const _Float16* __restrict__ kch, const _Float16* __restrict__ kcl,
    const _Float16* __restrict__ ksh, const _Float16* __restrict__ ksl,
    const _Float16* __restrict__ wqh, const _Float16* __restrict__ wql,
    const _Float16* __restrict__ wkh, const _Float16* __restrict__ wkl,
    const float* __restrict__ bq, const float* __restrict__ bk,
    _Float16* __restrict__ qzh, _Float16* __restrict__ qzl,
    _Float16* __restrict__ kzh, _Float16* __restrict__ kzl,
    int h0, int hcnt)
{
    const int inp = blockIdx.z;
    const _Float16* xch = inp ? kch : qch;
    const _Float16* xcl = inp ? kcl : qcl;
    const _Float16* xsh = inp ? ksh : qsh;
    const _Float16* xsl = inp ? ksl : qsl;
    const _Float16* wth = inp ? wkh : wqh;
    const _Float16* wtl = inp ? wkl : wql;
    const float* bias = inp ? bk : bq;
    _Float16* ozh = inp ? kzh : qzh;
    _Float16* ozl = inp ? kzl : qzl;

    const int m0 = blockIdx.x * 64;
    const int hc = blockIdx.y >> 2;
    const int n0 = (blockIdx.y & 3) * 128;
    __shared__ char lds[32768];
    const int tid = threadIdx.x, wv = tid >> 6, ln = tid & 63;
    const int wr = wv >> 1, wc = wv & 1, lm32 = ln & 31;

    const size_t abase = ((size_t)((m0 >> 5) + wr)) * 32 * 512 + ln * 8;
    const _Float16* pxc[2] = { xch + abase, xcl + abase };
    const _Float16* pxs[2] = { xsh + abase, xsl + abase };

    const char* spB[4]; int dpB[4];
#pragma unroll
    for (int u = 0; u < 4; ++u) {
        const int g = wv * 4 + u;
        const int jt = g >> 2, hl = (g >> 1) & 1, ks = g & 1;
        const _Float16* base = (hl ? wtl : wth) + (size_t)hc * 262144;
        spB[u] = (const char*)(base
                 + ((size_t)(((n0 + jt * 32) >> 5) * 32 + ks)) * 512 + ln * 8);
        dpB[u] = g * 1024;
    }

    f32x16 ach[2] = {}, acl[2] = {}, ash[2] = {}, asl[2] = {};

    auto LOADA = [&](int s, half8 (&ac)[2][2], half8 (&as)[2][2]) {
#pragma unroll
        for (int hl = 0; hl < 2; ++hl)
#pragma unroll
            for (int ks = 0; ks < 2; ++ks) {
                ac[hl][ks] = *(const half8*)(pxc[hl] + (2 * s + ks) * 512);
                as[hl][ks] = *(const half8*)(pxs[hl] + (2 * s + ks) * 512);
            }
    };
    auto STAGEB = [&](int s, int buf) {
#pragma unroll
        for (int u = 0; u < 4; ++u)
            gll16(spB[u] + (size_t)s * 2048, lds + buf + dpB[u]);
    };
    auto MSTEP = [&](int buf, half8 (&ac)[2][2], half8 (&as)[2][2]) {
        half8 w0[2][2], w1[2][2];
#pragma unroll
        for (int ks = 0; ks < 2; ++ks)
#pragma unroll
            for (int j = 0; j < 2; ++j) {
                const int gb = (wc * 2 + j) * 4 + ks;
                w0[ks][j] = *(const half8*)(lds + buf + gb * 1024 + ln * 16);
                w1[ks][j] = *(const half8*)(lds + buf + (gb + 2) * 1024 + ln * 16);
            }
        __builtin_amdgcn_s_setprio(1);
#pragma unroll
        for (int ks = 0; ks < 2; ++ks)
#pragma unroll
            for (int j = 0; j < 2; ++j) {
                ach[j] = MFMA32(ac[0][ks], w0[ks][j], ach[j]);
                acl[j] = MFMA32(ac[0][ks], w1[ks][j], acl[j]);
                acl[j] = MFMA32(ac[1][ks], w0[ks][j], acl[j]);
                ash[j] = MFMA32(as[0][ks], w0[ks][j], ash[j]);
                asl[j] = MFMA32(as[0][ks], w1[ks][j], asl[j]);
                asl[j] = MFMA32(as[1][ks], w0[ks][j], asl[j]);
            }
        __builtin_amdgcn_s_setprio(0);
    };

    half8 Ac0[2][2], As0[2][2], Ac1[2][2], As1[2][2];
    LOADA(0, Ac0, As0); STAGEB(0, 0);
    const int NS = 16;
    for (int s = 0; s < NS; s += 2) {
        __syncthreads();
        STAGEB(s + 1, 16384); LOADA(s + 1, Ac1, As1);
        MSTEP(0, Ac0, As0);
        __syncthreads();
        if (s + 2 < NS) { STAGEB(s + 2, 0); LOADA(s + 2, Ac0, As0); }
        MSTEP(16384, Ac1, As1);
    }

    const float LS = 1.0f / 4096.0f;
    const int b = m0 >> 10, tbase = m0 & 1023;
    const size_t zz = (size_t)(b * hcnt + hc);
    const size_t zb = zz << 20;
    __syncthreads();
    // LDS-repack epilogue: 2 plane rounds (hi, lo), 32KB frag tile each.
#pragma unroll
    for (int p = 0; p < 2; ++p) {
        if (p) __syncthreads();
#pragma unroll
        for (int j = 0; j < 2; ++j) {
            const int nloc = wc * 64 + j * 32 + lm32;
            const float bval = bias[(size_t)(h0 + hc) * 512 + n0 + nloc];
            const int kk = 2 * nloc;
#pragma unroll
            for (int r = 0; r < 16; ++r) {
                const int mloc = wr * 32 + ROWOF(r, ln);
                float yc = ach[j][r] + acl[j][r] * LS + bval;
                float ys = ash[j][r] + asl[j][r] * LS;
                float inv = 1.0f / sqrtf(fmaxf(yc * yc + ys * ys, 1e-36f));
                _Float16 c_h, c_l, s_h, s_l;
                split2(yc * inv, c_h, c_l);
                split2(ys * inv, s_h, s_l);
                half2v pr;
                pr[0] = p ? c_l : c_h;
                pr[1] = p ? s_l : s_h;
                *(half2v*)(lds + ((mloc >> 5) * 16 + (kk >> 4)) * 1024
                    + (mloc & 31) * 16 + 512 * ((kk >> 3) & 1) + (kk & 7) * 2) = pr;
            }
        }
        __syncthreads();
        _Float16* op = p ? ozl : ozh;
#pragma unroll
        for (int w = 0; w < 8; ++w) {
            const int u = w * 256 + tid;
            const int f = u >> 6, within = u & 63;
            const int ms = f >> 4, kf = f & 15;
            *(half8*)(op + zb + (((size_t)(tbase >> 5) + ms) * 64 + (n0 >> 3) + kf) * 512
                      + within * 8) = *(const half8*)(lds + f * 1024 + within * 16);
        }
    }
}

// ---------------------------------------------------------------------------
// proj_v: same GEMM, epilogue -> vT planes (frag M=512 d, K=1024 t) via per-plane
// LDS transpose [128][80] + frag-ordered coalesced copy-out.
// ---------------------------------------------------------------------------
__global__ __launch_bounds__(256, 2) void proj_v(
    const _Float16* __restrict__ xch, const _Float16* __restrict__ xcl,
    const _Float16* __restrict__ xsh, const _Float16* __restrict__ xsl,
    const _Float16* __restrict__ wth, const _Float16* __restrict__ wtl,
    const float* __restrict__ bias,
    _Float16* __restrict__ vc_h, _Float16* __restrict__ vc_l,
    _Float16* __restrict__ vs_h, _Float16* __restrict__ vs_l,
    int h0, int hcnt)
{
    const int m0 = blockIdx.x * 64;
    const int hc = blockIdx.y >> 2;
    const int n0 = (blockIdx.y & 3) * 128;
    __shared__ char lds[32768];
    const int tid = threadIdx.x, wv = tid >> 6, ln = tid & 63;
    const int wr = wv >> 1, wc = wv & 1, lm32 = ln & 31;

    const size_t abase = ((size_t)((m0 >> 5) + wr)) * 32 * 512 + ln * 8;
    const _Float16* pxc[2] = { xch + abase, xcl + abase };
    const _Float16* pxs[2] = { xsh + abase, xsl + abase };

    const char* spB[4]; int dpB[4];
#pragma unroll
    for (int u = 0; u < 4; ++u) {
        const int g = wv * 4 + u;
        const int jt = g >> 2, hl = (g >> 1) & 1, ks = g & 1;
        const _Float16* base = (hl ? wtl : wth) + (size_t)hc * 262144;
        spB[u] = (const char*)(base
                 + ((size_t)(((n0 + jt * 32) >> 5) * 32 + ks)) * 512 + ln * 8);
        dpB[u] = g * 1024;
    }

    f32x16 ach[2] = {}, acl[2] = {}, ash[2] = {}, asl[2] = {};

    auto LOADA = [&](int s, half8 (&ac)[2][2], half8 (&as)[2][2]) {
#pragma unroll
        for (int hl = 0; hl < 2; ++hl)
#pragma unroll
            for (int ks = 0; ks < 2; ++ks) {
                ac[hl][ks] = *(const half8*)(pxc[hl] + (2 * s + ks) * 512);
                as[hl][ks] = *(const half8*)(pxs[hl] + (2 * s + ks) * 512);
            }
    };
    auto STAGEB = [&](int s, int buf) {
#pragma unroll
        for (int u = 0; u < 4; ++u)
            gll16(spB[u] + (size_t)s * 2048, lds + buf + dpB[u]);
    };
    auto MSTEP = [&](int buf, half8 (&ac)[2][2], half8 (&as)[2][2]) {
        half8 w0[2][2], w1[2][2];
#pragma unroll
        for (int ks = 0; ks < 2; ++ks)
#pragma unroll
            for (int j = 0; j < 2; ++j) {
                const int gb = (wc * 2 + j) * 4 + ks;
                w0[ks][j] = *(const half8*)(lds + buf + gb * 1024 + ln * 16);
                w1[ks][j] = *(const half8*)(lds + buf + (gb + 2) * 1024 + ln * 16);
            }
        __builtin_amdgcn_s_setprio(1);
#pragma unroll
        for (int ks = 0; ks < 2; ++ks)
#pragma unroll
            for (int j = 0; j < 2; ++j) {
                ach[j] = MFMA32(ac[0][ks], w0[ks][j], ach[j]);
                acl[j] = MFMA32(ac[0][ks], w1[ks][j], acl[j]);
                acl[j] = MFMA32(ac[1][ks], w0[ks][j], acl[j]);
                ash[j] = MFMA32(as[0][ks], w0[ks][j], ash[j]);
                asl[j] = MFMA32(as[0][ks], w1[ks][j], asl[j]);
                asl[j] = MFMA32(as[1][ks], w0[ks][j], asl[j]);
            }
        __builtin_amdgcn_s_setprio(0);
    };

    half8 Ac0[2][2], As0[2][2], Ac1[2][2], As1[2][2];
    LOADA(0, Ac0, As0); STAGEB(0, 0);
    const int NS = 16;
    for (int s = 0; s < NS; s += 2) {
        __syncthreads();
        STAGEB(s + 1, 16384); LOADA(s + 1, Ac1, As1);
        MSTEP(0, Ac0, As0);
        __syncthreads();
        if (s + 2 < NS) { STAGEB(s + 2, 0); LOADA(s + 2, Ac0, As0); }
        MSTEP(16384, Ac1, As1);
    }

    const float LS = 1.0f / 4096.0f;
    const int b = m0 >> 10, tbase = m0 & 1023;
    const size_t zz = (size_t)(b * hcnt + hc);
    const size_t zvb = zz * 524288;
    _Float16* T = (_Float16*)lds;
#pragma unroll
    for (int p = 0; p < 4; ++p) {
        __syncthreads();
#pragma unroll
        for (int j = 0; j < 2; ++j) {
            const int dloc = wc * 64 + j * 32 + lm32;
            const float bval = bias[(size_t)(h0 + hc) * 512 + n0 + dloc];
#pragma unroll
            for (int r = 0; r < 16; ++r) {
                const int tloc = wr * 32 + ROWOF(r, ln);
                float yc = ach[j][r] + acl[j][r] * LS + bval;
                float ys = ash[j][r] + asl[j][r] * LS;
                float inv = 1.0f / sqrtf(fmaxf(yc * yc + ys * ys, 1e-36f));
                _Float16 hh, ll;
                if (p < 2) split2(yc * inv, hh, ll);
                else       split2(ys * inv, hh, ll);
                T[dloc * 80 + tloc] = (p & 1) ? ll : hh;
            }
        }
        __syncthreads();
        _Float16* op = (p == 0) ? vc_h : (p == 1) ? vc_l : (p == 2) ? vs_h : vs_l;
#pragma unroll
        for (int w = 0; w < 4; ++w) {
            const int u = w * 256 + tid;
            const int f = u >> 6, within = u & 63;
            const int ds_ = f >> 2, tf = f & 3;
            const int d = ds_ * 32 + (within & 31);
            const int tl = tf * 16 + (within >> 5) * 8;
            half8 vv = *(const half8*)(T + d * 80 + tl);
            *(half8*)(op + zvb + (((size_t)((n0 >> 5) + ds_)) * 64 + (tbase >> 4) + tf) * 512
                      + within * 8) = vv;
        }
    }
}

// ---------------------------------------------------------------------------
// scores: P[t][T] = exp( (qz . kz)/512 ), split-fp16, written directly in pv's
// A-frag layout (Kd16=64). No softmax normalization (cancels in pv's z/|z|).
// Main loop identical to r7. Epilogue: 2 rounds (hi, lo), 32KB LDS frag tile
// -> coalesced 16B copy-out.
// ---------------------------------------------------------------------------
__global__ __launch_bounds__(256, 2) void scores_mfma(
    const _Float16* __restrict__ qzh, const _Float16* __restrict__ qzl,
    const _Float16* __restrict__ kzh, const _Float16* __restrict__ kzl,
    _Float16* __restrict__ Ph, _Float16* __restrict__ Pl, int Z)
{
    const int wg = xcdswz(blockIdx.x, Z * 64);
    const int z = wg >> 6;
    const int rem = wg & 63;
    const int m0 = (rem & 7) << 7, n0 = (rem >> 3) << 7;
    __shared__ char lds[32768];
    const size_t zb = (size_t)z << 20;
    const int tid = threadIdx.x, wv = tid >> 6, ln = tid & 63;
    const int wr = wv >> 1, wc = wv & 1, lm32 = ln & 31;

    const _Float16* pa[2] = { qzh + zb + ln * 8, qzl + zb + ln * 8 };
    const char* spB[4]; int dpB[4];
#pragma unroll
    for (int u = 0; u < 4; ++u) {
        const int g = wv * 4 + u;
        const int jt = g >> 2, hl = (g >> 1) & 1, ks = g & 1;
        spB[u] = (const char*)((hl ? kzl : kzh) + zb
                 + ((size_t)(((n0 + jt * 32) >> 5) * 64 + ks)) * 512 + ln * 8);
        dpB[u] = g * 1024;
    }

    f32x16 acch[2][2] = {}, accl[2][2] = {};

    auto LOADA = [&](int s, half8 (&a)[2][2][2]) {
#pragma unroll
        for (int hl = 0; hl < 2; ++hl)
#pragma unroll
            for (int i = 0; i < 2; ++i)
#pragma unroll
                for (int ks = 0; ks < 2; ++ks)
                    a[hl][i][ks] = *(const half8*)(pa[hl]
                        + ((size_t)((m0 >> 5) + wr * 2 + i) * 64 + 2 * s + ks) * 512);
    };
    auto STAGEB = [&](int s, int buf) {
#pragma unroll
        for (int u = 0; u < 4; ++u)
            gll16(spB[u] + (size_t)s * 2048, lds + buf + dpB[u]);
    };
    auto MSTEP = [&](int buf, half8 (&a)[2][2][2]) {
        half8 bh[2][2], bl[2][2];
#pragma unroll
        for (int ks = 0; ks < 2; ++ks)
#pragma unroll
            for (int j = 0; j < 2; ++j) {
                const int gb = (wc * 2 + j) * 4 + ks;
                bh[ks][j] = *(const half8*)(lds + buf + gb * 1024 + ln * 16);
                bl[ks][j] = *(const half8*)(lds + buf + (gb + 2) * 1024 + ln * 16);
            }
        __builtin_amdgcn_s_setprio(1);
#pragma unroll
        for (int ks = 0; ks < 2; ++ks)
#pragma unroll
            for (int i = 0; i < 2; ++i)
#pragma unroll
                for (int j = 0; j < 2; ++j) {
                    acch[i][j] = MFMA32(a[0][i][ks], bh[ks][j], acch[i][j]);
                    accl[i][j] = MFMA32(a[0][i][ks], bl[ks][j], accl[i][j]);
                    accl[i][j] = MFMA32(a[1][i][ks], bh[ks][j], accl[i][j]);
                }
        __builtin_amdgcn_s_setprio(0);
    };

    half8 A0[2][2][2], A1[2][2][2];
    LOADA(0, A0); STAGEB(0, 0);
    const int NS = 32;
    for (int s = 0; s < NS; s += 2) {
        __syncthreads();
        STAGEB(s + 1, 16384); LOADA(s + 1, A1);
        MSTEP(0, A0);
        __syncthreads();
        if (s + 2 < NS) { STAGEB(s + 2, 0); LOADA(s + 2, A0); }
        MSTEP(16384, A1);
    }

    const float LS = 1.0f / 4096.0f, SC = 1.0f / 512.0f;
    __syncthreads();
    // Epilogue: P = exp(S/512), split-fp16, frag layout. 2 rounds (hi, lo):
    // 32 frags x 1KB = 32KB LDS per round, then coalesced copy-out.
#pragma unroll
    for (int p = 0; p < 2; ++p) {
        if (p) __syncthreads();
#pragma unroll
        for (int i = 0; i < 2; ++i)
#pragma unroll
            for (int j = 0; j < 2; ++j)
#pragma unroll
                for (int r = 0; r < 16; ++r) {
                    const int tl = wr * 64 + i * 32 + ROWOF(r, ln);   // 0..127
                    const int Tl = wc * 64 + j * 32 + lm32;           // 0..127
                    float Pv = expf((acch[i][j][r] + accl[i][j][r] * LS) * SC);
                    _Float16 hh, ll;
                    split2(Pv, hh, ll);
                    const int fl = (tl >> 5) * 8 + (Tl >> 4);         // 0..31
                    *(_Float16*)(lds + fl * 1024 + (tl & 31) * 16
                        + 512 * ((Tl >> 3) & 1) + (Tl & 7) * 2) = p ? ll : hh;
                }
        __syncthreads();
        _Float16* op = p ? Pl : Ph;
#pragma unroll
        for (int w = 0; w < 8; ++w) {
            const int u = w * 256 + tid;
            const int f = u >> 6, l = u & 63;
            const int ft = f >> 3, fT = f & 7;
            const size_t dst = zb + ((size_t)(((m0 >> 5) + ft) * 64
                               + (n0 >> 4) + fT)) * 512 + l * 8;
            *(half8*)(op + dst) = *(const half8*)(lds + f * 1024 + l * 16);
        }
    }
}

// ---------------------------------------------------------------------------
// pv: out = P @ vz, normalize (cancels softmax denom), split -> rcs planes
// (frag M=2048, K=4096). Identical to r7.
// ---------------------------------------------------------------------------
__global__ __launch_bounds__(256, 2) void pv_mfma(
    const _Float16* __restrict__ Ph, const _Float16* __restrict__ Pl,
    const _Float16* __restrict__ vch, const _Float16* __restrict__ vcl,
    const _Float16* __restrict__ vsh, const _Float16* __restrict__ vsl,
    _Float16* __restrict__ rch, _Float16* __restrict__ rcl,
    _Float16* __restrict__ rsh, _Float16* __restrict__ rsl,
    int h0, int hcnt, int Z)
{
    const int wg = xcdswz(blockIdx.x, Z * 64);
    const int z = wg >> 6;
    const int rem = wg & 63;
    const int m0 = (rem & 7) << 7, n0 = (rem >> 3) << 6;
    __shared__ char lds[32768];
    const int tid = threadIdx.x, wv = tid >> 6, ln = tid & 63;
    const int wr = wv >> 1, wc = wv & 1, lm32 = ln & 31;

    const size_t zb = (size_t)z << 20, zvb = (size_t)z * 524288;
    const _Float16* pa[2] = { Ph + zb + ln * 8, Pl + zb + ln * 8 };
    const char* spB[4]; int dpB[4];
#pragma unroll
    for (int u = 0; u < 4; ++u) {
        const int g = wv * 4 + u;
        const int pl = g >> 3, dt = (g >> 2) & 1, hl = (g >> 1) & 1, ks = g & 1;
        const _Float16* base = pl ? (hl ? vsl : vsh) : (hl ? vcl : vch);
        spB[u] = (const char*)(base + zvb
                 + ((size_t)(((n0 + dt * 32) >> 5) * 64 + ks)) * 512 + ln * 8);
        dpB[u] = g * 1024;
    }

    f32x16 ac_h[2] = {}, ac_l[2] = {}, as_h[2] = {}, as_l[2] = {};

    auto LOADA = [&](int s, half8 (&a)[2][2][2]) {
#pragma unroll
        for (int hl = 0; hl < 2; ++hl)
#pragma unroll
            for (int i = 0; i < 2; ++i)
#pragma unroll
                for (int ks = 0; ks < 2; ++ks)
                    a[hl][i][ks] = *(const half8*)(pa[hl]
                        + ((size_t)((m0 >> 5) + wr * 2 + i) * 64 + 2 * s + ks) * 512);
    };
    auto STAGEB = [&](int s, int buf) {
#pragma unroll
        for (int u = 0; u < 4; ++u)
            gll16(spB[u] + (size_t)s * 2048, lds + buf + dpB[u]);
    };
    auto MSTEP = [&](int buf, half8 (&a)[2][2][2]) {
        half8 vc[2][2], vs[2][2];
#pragma unroll
        for (int hl = 0; hl < 2; ++hl)
#pragma unroll
            for (int ks = 0; ks < 2; ++ks) {
                vc[hl][ks] = *(const half8*)(lds + buf + (wc * 4 + hl * 2 + ks) * 1024 + ln * 16);
                vs[hl][ks] = *(const half8*)(lds + buf + (8 + wc * 4 + hl * 2 + ks) * 1024 + ln * 16);
            }
        __builtin_amdgcn_s_setprio(1);
#pragma unroll
        for (int ks = 0; ks < 2; ++ks)
#pragma unroll
            for (int i = 0; i < 2; ++i) {
                ac_h[i] = MFMA32(a[0][i][ks], vc[0][ks], ac_h[i]);
                ac_l[i] = MFMA32(a[0][i][ks], vc[1][ks], ac_l[i]);
                ac_l[i] = MFMA32(a[1][i][ks], vc[0][ks], ac_l[i]);
                as_h[i] = MFMA32(a[0][i][ks], vs[0][ks], as_h[i]);
                as_l[i] = MFMA32(a[0][i][ks], vs[1][ks], as_l[i]);
                as_l[i] = MFMA32(a[1][i][ks], vs[0][ks], as_l[i]);
            }
        __builtin_amdgcn_s_setprio(0);
    };

    half8 A0[2][2][2], A1[2][2][2];
    LOADA(0, A0); STAGEB(0, 0);
    const int NS = 32;
    for (int s = 0; s < NS; s += 2) {
        __syncthreads();
        STAGEB(s + 1, 16384); LOADA(s + 1, A1);
        MSTEP(0, A0);
        __syncthreads();
        if (s + 2 < NS) { STAGEB(s + 2, 0); LOADA(s + 2, A0); }
        MSTEP(16384, A1);
    }
    const float LS = 1.0f / 4096.0f;
    const int b = z / hcnt, hg = h0 + z % hcnt;
    const size_t mrow = (size_t)((b * 1024 + m0) >> 5);
    const size_t kcol = (size_t)(hg * 512 + n0) >> 4;
    __syncthreads();
#pragma unroll
    for (int p = 0; p < 4; ++p) {
        if (p) __syncthreads();
#pragma unroll
        for (int i = 0; i < 2; ++i)
#pragma unroll
            for (int r = 0; r < 16; ++r) {
                const int mloc = wr * 64 + i * 32 + ROWOF(r, ln);
                const int kloc = wc * 32 + lm32;
                float zc = ac_h[i][r] + ac_l[i][r] * LS;
                float zs = as_h[i][r] + as_l[i][r] * LS;
                float inv = 1.0f / sqrtf(fmaxf(zc * zc + zs * zs, 1e-36f));
                _Float16 hh, ll;
                if (p < 2) split2(zc * inv, hh, ll);
                else       split2(zs * inv, hh, ll);
                *(_Float16*)(lds + ((mloc >> 5) * 4 + (kloc >> 4)) * 1024
                    + (mloc & 31) * 16 + 512 * ((kloc >> 3) & 1) + (kloc & 7) * 2)
                    = (p & 1) ? ll : hh;
            }
        __syncthreads();
        _Float16* op = (p == 0) ? rch : (p == 1) ? rcl : (p == 2) ? rsh : rsl;
#pragma unroll
        for (int w = 0; w < 4; ++w) {
            const int u = w * 256 + tid;
            const int f = u >> 6, within = u & 63;
            const int ms = f >> 2, kf = f & 3;
            *(half8*)(op + ((mrow + ms) * 256 + kcol + kf) * 512 + within * 8)
                = *(const half8*)(lds + f * 1024 + within * 16);
        }
    }
}

// ---------------------------------------------------------------------------
// final (K-split): partial z = rz @ wo. Identical to r7.
// ---------------------------------------------------------------------------
__global__ __launch_bounds__(256, 2) void final_mfma(
    const _Float16* __restrict__ rch, const _Float16* __restrict__ rcl,
    const _Float16* __restrict__ rsh, const _Float16* __restrict__ rsl,
    const _Float16* __restrict__ woh, const _Float16* __restrict__ wol,
    float* __restrict__ pbuf)
{
    const int m0 = blockIdx.x * 64, n0 = blockIdx.y * 128;
    const int kspl = blockIdx.z;
    const int kf = kspl * 64;
    __shared__ char lds[32768];
    const int tid = threadIdx.x, wv = tid >> 6, ln = tid & 63;
    const int wr = wv >> 1, wc = wv & 1, lm32 = ln & 31;

    const size_t abase = ((size_t)((m0 >> 5) + wr) * 256 + kf) * 512 + ln * 8;
    const _Float16* prc[2] = { rch + abase, rcl + abase };
    const _Float16* prs[2] = { rsh + abase, rsl + abase };
    const char* spB[4]; int dpB[4];
#pragma unroll
    for (int u = 0; u < 4; ++u) {
        const int g = wv * 4 + u;
        const int jt = g >> 2, hl = (g >> 1) & 1, ks = g & 1;
        spB[u] = (const char*)((hl ? wol : woh)
                 + ((size_t)(((n0 + jt * 32) >> 5) * 256 + kf + ks)) * 512 + ln * 8);
        dpB[u] = g * 1024;
    }

    f32x16 rr_h[2] = {}, rr_l[2] = {}, ri_h[2] = {}, ri_l[2] = {};

    auto LOADA = [&](int s, half8 (&ac)[2][2], half8 (&as)[2][2]) {
#pragma unroll
        for (int hl = 0; hl < 2; ++hl)
#pragma unroll
            for (int ks = 0; ks < 2; ++ks) {
                ac[hl][ks] = *(const half8*)(prc[hl] + (2 * s + ks) * 512);
                as[hl][ks] = *(const half8*)(prs[hl] + (2 * s + ks) * 512);
            }
    };
    auto STAGEB = [&](int s, int buf) {
#pragma unroll
        for (int u = 0; u < 4; ++u)
            gll16(spB[u] + (size_t)s * 2048, lds + buf + dpB[u]);
    };
    auto MSTEP = [&](int buf, half8 (&ac)[2][2], half8 (&as)[2][2]) {
        half8 w0[2][2], w1[2][2];
#pragma unroll
        for (int ks = 0; ks < 2; ++ks)
#pragma unroll
            for (int j = 0; j < 2; ++j) {
                const int gb = (wc * 2 + j) * 4 + ks;
                w0[ks][j] = *(const half8*)(lds + buf + gb * 1024 + ln * 16);
                w1[ks][j] = *(const half8*)(lds + buf + (gb + 2) * 1024 + ln * 16);
            }
        __builtin_amdgcn_s_setprio(1);
#pragma unroll
        for (int ks = 0; ks < 2; ++ks)
#pragma unroll
            for (int j = 0; j < 2; ++j) {
                rr_h[j] = MFMA32(ac[0][ks], w0[ks][j], rr_h[j]);
                rr_l[j] = MFMA32(ac[0][ks], w1[ks][j], rr_l[j]);
                rr_l[j] = MFMA32(ac[1][ks], w0[ks][j], rr_l[j]);
                ri_h[j] = MFMA32(as[0][ks], w0[ks][j], ri_h[j]);
                ri_l[j] = MFMA32(as[0][ks], w1[ks][j], ri_l[j]);
                ri_l[j] = MFMA32(as[1][ks], w0[ks][j], ri_l[j]);
            }
        __builtin_amdgcn_s_setprio(0);
    };

    half8 Ac0[2][2], As0[2][2], Ac1[2][2], As1[2][2];
    LOADA(0, Ac0, As0); STAGEB(0, 0);
    const int NS = 32;
    for (int s = 0; s < NS; s += 2) {
        __syncthreads();
        STAGEB(s + 1, 16384); LOADA(s + 1, Ac1, As1);
        MSTEP(0, Ac0, As0);
        __syncthreads();
        if (s + 2 < NS) { STAGEB(s + 2, 0); LOADA(s + 2, Ac0, As0); }
        MSTEP(16384, Ac1, As1);
    }
    const float LS = 1.0f / 4096.0f;
#pragma unroll
    for (int j = 0; j < 2; ++j) {
        const int ng = n0 + wc * 64 + j * 32 + lm32;
#pragma unroll
        for (int r = 0; r < 16; ++r) {
            const int mg = m0 + wr * 32 + ROWOF(r, ln);
            float2 v;
            v.x = rr_h[j][r] + rr_l[j][r] * LS;
            v.y = ri_h[j][r] + ri_l[j][r] * LS;
            *(float2*)&pbuf[((size_t)(kspl * 2048 + mg) * 512 + ng) * 2] = v;
        }
    }
}

// ---------------------------------------------------------------------------
// combine: out[m][n] = atan2(sum zi, sum zr + bo[n]) / pi
// ---------------------------------------------------------------------------
__global__ __launch_bounds__(256) void final_combine(
    const float* __restrict__ pbuf, const float* __restrict__ bo,
    float* __restrict__ out, int KS)
{
    const int m = blockIdx.x, t = threadIdx.x;
    float4 acc = {0.f, 0.f, 0.f, 0.f};
    for (int s = 0; s < KS; ++s) {
        float4 v = *(const float4*)&pbuf[(size_t)(s * 2048 + m) * 1024 + t * 4];
        acc.x += v.x; acc.y += v.y; acc.z += v.z; acc.w += v.w;
    }
    const int n0 = t * 2;
    out[(size_t)m * 512 + n0]     = atan2f(acc.y, acc.x + bo[n0]) / PI_F;
    out[(size_t)m * 512 + n0 + 1] = atan2f(acc.w, acc.z + bo[n0 + 1]) / PI_F;
}

// ---------------------------------------------------------------------------
extern "C" void kernel_launch(void* const* d_in, const int* in_sizes, int n_in,
                              void* d_out, int out_size, void* d_ws, size_t ws_size,
                              hipStream_t stream)
{
    (void)in_sizes; (void)n_in; (void)out_size;
    const float* query    = (const float*)d_in[0];
    const float* keyvalue = (const float*)d_in[1];
    const float* wq = (const float*)d_in[2];
    const float* bq = (const float*)d_in[3];
    const float* wk = (const float*)d_in[4];
    const float* bk = (const float*)d_in[5];
    const float* wv = (const float*)d_in[6];
    const float* bv = (const float*)d_in[7];
    const float* wo = (const float*)d_in[8];
    const float* bo = (const float*)d_in[9];
    float* out = (float*)d_out;

    int hcnt;
    if (ws_size >= (size_t)320 * 1024 * 1024) hcnt = 8;
    else if (ws_size >= (size_t)240 * 1024 * 1024) hcnt = 4;
    else hcnt = 2;
    const int Z = 2 * hcnt;
    const int KS = (hcnt == 2) ? 2 : 4;

    char* p = (char*)d_ws;
    auto alloc = [&](size_t bytes) {
        char* r = p;
        p += (bytes + 255) & ~(size_t)255;
        return r;
    };
    const size_t PLX = (size_t)2048 * 512;
    _Float16* xq[4]; for (int i = 0; i < 4; ++i) xq[i] = (_Float16*)alloc(PLX * 2);
    _Float16* xk[4]; for (int i = 0; i < 4; ++i) xk[i] = (_Float16*)alloc(PLX * 2);
    _Float16* woT[2]; for (int i = 0; i < 2; ++i) woT[i] = (_Float16*)alloc((size_t)512 * 4096 * 2);
    const size_t WTE = (size_t)hcnt * 512 * 512;
    _Float16* wqT[2]; for (int i = 0; i < 2; ++i) wqT[i] = (_Float16*)alloc(WTE * 2);
    _Float16* wkT[2]; for (int i = 0; i < 2; ++i) wkT[i] = (_Float16*)alloc(WTE * 2);
    _Float16* wvT[2]; for (int i = 0; i < 2; ++i) wvT[i] = (_Float16*)alloc(WTE * 2);
    const size_t QZE = (size_t)Z * 1024 * 1024;
    _Float16* qz[2]; for (int i = 0; i < 2; ++i) qz[i] = (_Float16*)alloc(QZE * 2);
    _Float16* kz[2]; for (int i = 0; i < 2; ++i) kz[i] = (_Float16*)alloc(QZE * 2);
    // P planes take the slot the f32 S array used (same total bytes).
    _Float16* Ph = (_Float16*)alloc(QZE * 2);
    _Float16* Pl = (_Float16*)alloc(QZE * 2);
    const size_t VTE = (size_t)Z * 512 * 1024;
    _Float16* vT[4]; for (int i = 0; i < 4; ++i) vT[i] = (_Float16*)alloc(VTE * 2);
    const size_t RCE = (size_t)2048 * 4096;
    _Float16* rcs[4];
    if (hcnt == 8) {
        for (int i = 0; i < 4; ++i) rcs[i] = (_Float16*)((char*)qz[0] + (size_t)i * RCE * 2);
    } else {
        for (int i = 0; i < 4; ++i) rcs[i] = (_Float16*)alloc(RCE * 2);
    }
    // pbuf overlays Ph (and spills into the adjacent Pl): P dead after last pv.
    float* pbuf = (float*)Ph;

    dim3 blk(256);

    encode_phasor<<<dim3(64, 2, 2), blk, 0, stream>>>(
        query, keyvalue,
        xq[0], xq[1], xq[2], xq[3], xk[0], xk[1], xk[2], xk[3]);
    tsplit64<<<dim3(64, 8, 1), blk, 0, stream>>>(wo, woT[0], woT[1], 4096, 512);

    for (int c = 0; c < 8 / hcnt; ++c) {
        const int h0 = c * hcnt;
        tsplit_qkv<<<dim3(8, 8, 3 * hcnt), blk, 0, stream>>>(
            wq + (size_t)h0 * 262144, wk + (size_t)h0 * 262144, wv + (size_t)h0 * 262144,
            wqT[0], wqT[1], wkT[0], wkT[1], wvT[0], wvT[1], hcnt);

        proj_qk<<<dim3(32, hcnt * 4, 2), blk, 0, stream>>>(
            xq[0], xq[1], xq[2], xq[3], xk[0], xk[1], xk[2], xk[3],
            wqT[0], wqT[1], wkT[0], wkT[1], bq, bk,
            qz[0], qz[1], kz[0], kz[1], h0, hcnt);
        proj_v<<<dim3(32, hcnt * 4), blk, 0, stream>>>(
            xk[0], xk[1], xk[2], xk[3], wvT[0], wvT[1], bv,
            vT[0], vT[1], vT[2], vT[3], h0, hcnt);

        scores_mfma<<<dim3(Z * 64), blk, 0, stream>>>(
            qz[0], qz[1], kz[0], kz[1], Ph, Pl, Z);
        pv_mfma<<<dim3(Z * 64), blk, 0, stream>>>(
            Ph, Pl, vT[0], vT[1], vT[2], vT[3],
            rcs[0], rcs[1], rcs[2], rcs[3], h0, hcnt, Z);
    }

    final_mfma<<<dim3(32, 4, KS), blk, 0, stream>>>(
        rcs[0], rcs[1], rcs[2], rcs[3], woT[0], woT[1], pbuf);
    final_combine<<<dim3(2048), blk, 0, stream>>>(pbuf, bo, out, KS);
}